// Round 1
// 5590.201 us; speedup vs baseline: 1.7879x; 1.7879x over previous
//
#include <hip/hip_runtime.h>
#include <hip/hip_bf16.h>

// Problem constants
#define BDIM 8
#define TDIM 2048
#define CDIM 1024
#define HDIM 4096
#define EDIM 8
#define CAPACITY 320
#define MTOK (BDIM*TDIM)          // 16384
#define MCHUNK 2048               // router M-chunk
#define NCHUNKS (MTOK/MCHUNK)     // 8
#define EROWS (BDIM*CAPACITY)     // 2560 rows per expert
#define NROWS (EDIM*EROWS)        // 20480 total slots

typedef __attribute__((ext_vector_type(8))) short bf16x8;
typedef __attribute__((ext_vector_type(8))) _Float16 f16x8;
typedef __attribute__((ext_vector_type(4))) float f32x4;

__device__ __forceinline__ unsigned short f2bf(float f){
    __hip_bfloat16 h = __float2bfloat16(f);
    return *reinterpret_cast<unsigned short*>(&h);
}

// exact 2-term fp16 split: v = hi + lo + O(2^-22 * |v|)
__device__ __forceinline__ void f32_split(float v, unsigned short& h, unsigned short& l){
    _Float16 hh = (_Float16)v;         // RN
    float r = v - (float)hh;           // exact in fp32
    _Float16 ll = (_Float16)r;
    h = __builtin_bit_cast(unsigned short, hh);
    l = __builtin_bit_cast(unsigned short, ll);
}

// ---------------------------------------------------------------------------
// K0: transpose + fp32->bf16 convert.  in: [z][R][Ccol] f32, out: [z][Ccol][R] bf16
// grid: (Ccol/32, R/32, Z), block 256    (expert weights)
// ---------------------------------------------------------------------------
__global__ __launch_bounds__(256) void transpose_convert(
    const float* __restrict__ in, unsigned short* __restrict__ out, int R, int Ccol)
{
    int z = blockIdx.z;
    in  += (size_t)z * R * Ccol;
    out += (size_t)z * R * Ccol;
    __shared__ float tile[32][33];
    int r0 = blockIdx.y * 32, c0 = blockIdx.x * 32;
    int tid = threadIdx.x;
    int lr = tid >> 5, lc = tid & 31;
    #pragma unroll
    for (int it = 0; it < 4; it++)
        tile[it*8 + lr][lc] = in[(size_t)(r0 + it*8 + lr) * Ccol + c0 + lc];
    __syncthreads();
    #pragma unroll
    for (int it = 0; it < 4; it++){
        float v = tile[lc][it*8 + lr];
        out[(size_t)(c0 + it*8 + lr) * R + r0 + lc] = f2bf(v);
    }
}

// ---------------------------------------------------------------------------
// K0b: transpose + fp32 -> fp16 hi/lo split.  in: [R][Ccol] f32, out hi/lo: [Ccol][R]
// grid: (Ccol/32, R/32), block 256    (router weights)
// ---------------------------------------------------------------------------
__global__ __launch_bounds__(256) void transpose_split(
    const float* __restrict__ in, unsigned short* __restrict__ hi,
    unsigned short* __restrict__ lo, int R, int Ccol)
{
    __shared__ float tile[32][33];
    int r0 = blockIdx.y * 32, c0 = blockIdx.x * 32;
    int tid = threadIdx.x;
    int lr = tid >> 5, lc = tid & 31;
    #pragma unroll
    for (int it = 0; it < 4; it++)
        tile[it*8 + lr][lc] = in[(size_t)(r0 + it*8 + lr) * Ccol + c0 + lc];
    __syncthreads();
    #pragma unroll
    for (int it = 0; it < 4; it++){
        float v = tile[lc][it*8 + lr];
        unsigned short h, l;
        f32_split(v, h, l);
        size_t o = (size_t)(c0 + it*8 + lr) * R + r0 + lc;
        hi[o] = h; lo[o] = l;
    }
}

// ---------------------------------------------------------------------------
// K0c: elementwise fp32 -> fp16 hi/lo split (x activations, [M][K] row-major)
// ---------------------------------------------------------------------------
__global__ __launch_bounds__(256) void split_f16(
    const float* __restrict__ in, unsigned short* __restrict__ hi,
    unsigned short* __restrict__ lo, size_t n4)
{
    size_t i = (size_t)blockIdx.x * 256 + threadIdx.x;
    if (i >= n4) return;
    float4 v = ((const float4*)in)[i];
    ushort4 h, l;
    f32_split(v.x, h.x, l.x);
    f32_split(v.y, h.y, l.y);
    f32_split(v.z, h.z, l.z);
    f32_split(v.w, h.w, l.w);
    ((ushort4*)hi)[i] = h;
    ((ushort4*)lo)[i] = l;
}

// ---------------------------------------------------------------------------
// K1/K2: fp32-accurate router GEMM via fp16x3 MFMA emulation.
// out = relu(A[M,K] @ Bt[N,K]^T + bias[N]),  A = Ahi+Alo, B = Bhi+Blo (exact split)
// C = Ahi*Bhi + Ahi*Blo + Alo*Bhi  (fp32 MFMA accum; dropped term <= 2^-22)
// 64x64 tile, BK=32, 256 threads (4 waves, each 32x32 via 2x2 mfma 16x16x32).
// mode 0: relu -> f16 hi/lo split outputs (outA=hi, outB=lo)
// mode 1: relu -> f32 output (outA)
// grid (M/64, N/64)
// ---------------------------------------------------------------------------
__global__ __launch_bounds__(256) void gemm_f16x3(
    const unsigned short* __restrict__ Ahi, const unsigned short* __restrict__ Alo,
    const unsigned short* __restrict__ Bthi, const unsigned short* __restrict__ Btlo,
    const float* __restrict__ bias, void* __restrict__ outA, void* __restrict__ outB,
    int M, int N, int K, int mode)
{
    __shared__ unsigned short AsH[64 * 40];
    __shared__ unsigned short AsL[64 * 40];
    __shared__ unsigned short BsH[64 * 40];
    __shared__ unsigned short BsL[64 * 40];
    int tid = threadIdx.x;
    int m0 = blockIdx.x * 64, n0 = blockIdx.y * 64;
    int lane = tid & 63, w = tid >> 6;
    int wm = w & 1, wn = w >> 1;
    int l15 = lane & 15, quad = lane >> 4;

    f32x4 acc[2][2];
    #pragma unroll
    for (int a = 0; a < 2; a++)
        #pragma unroll
        for (int bq = 0; bq < 2; bq++){ acc[a][bq].x=0.f; acc[a][bq].y=0.f; acc[a][bq].z=0.f; acc[a][bq].w=0.f; }

    int srow = tid >> 2, sseg = (tid & 3) * 8;
    size_t aoff = (size_t)(m0 + srow) * K + sseg;
    size_t boff = (size_t)(n0 + srow) * K + sseg;
    int woff = srow * 40 + sseg;

    for (int k0 = 0; k0 < K; k0 += 32){
        uint4 ah = *(const uint4*)(Ahi + aoff + k0);
        uint4 al = *(const uint4*)(Alo + aoff + k0);
        uint4 bh = *(const uint4*)(Bthi + boff + k0);
        uint4 bl = *(const uint4*)(Btlo + boff + k0);
        __syncthreads();
        *(uint4*)(AsH + woff) = ah;
        *(uint4*)(AsL + woff) = al;
        *(uint4*)(BsH + woff) = bh;
        *(uint4*)(BsL + woff) = bl;
        __syncthreads();
        f16x8 a0h = *(const f16x8*)(AsH + (wm*32 +  0 + l15) * 40 + quad*8);
        f16x8 a1h = *(const f16x8*)(AsH + (wm*32 + 16 + l15) * 40 + quad*8);
        f16x8 a0l = *(const f16x8*)(AsL + (wm*32 +  0 + l15) * 40 + quad*8);
        f16x8 a1l = *(const f16x8*)(AsL + (wm*32 + 16 + l15) * 40 + quad*8);
        f16x8 b0h = *(const f16x8*)(BsH + (wn*32 +  0 + l15) * 40 + quad*8);
        f16x8 b1h = *(const f16x8*)(BsH + (wn*32 + 16 + l15) * 40 + quad*8);
        f16x8 b0l = *(const f16x8*)(BsL + (wn*32 +  0 + l15) * 40 + quad*8);
        f16x8 b1l = *(const f16x8*)(BsL + (wn*32 + 16 + l15) * 40 + quad*8);
        // hi*hi
        acc[0][0] = __builtin_amdgcn_mfma_f32_16x16x32_f16(a0h, b0h, acc[0][0], 0, 0, 0);
        acc[0][1] = __builtin_amdgcn_mfma_f32_16x16x32_f16(a0h, b1h, acc[0][1], 0, 0, 0);
        acc[1][0] = __builtin_amdgcn_mfma_f32_16x16x32_f16(a1h, b0h, acc[1][0], 0, 0, 0);
        acc[1][1] = __builtin_amdgcn_mfma_f32_16x16x32_f16(a1h, b1h, acc[1][1], 0, 0, 0);
        // hi*lo
        acc[0][0] = __builtin_amdgcn_mfma_f32_16x16x32_f16(a0h, b0l, acc[0][0], 0, 0, 0);
        acc[0][1] = __builtin_amdgcn_mfma_f32_16x16x32_f16(a0h, b1l, acc[0][1], 0, 0, 0);
        acc[1][0] = __builtin_amdgcn_mfma_f32_16x16x32_f16(a1h, b0l, acc[1][0], 0, 0, 0);
        acc[1][1] = __builtin_amdgcn_mfma_f32_16x16x32_f16(a1h, b1l, acc[1][1], 0, 0, 0);
        // lo*hi
        acc[0][0] = __builtin_amdgcn_mfma_f32_16x16x32_f16(a0l, b0h, acc[0][0], 0, 0, 0);
        acc[0][1] = __builtin_amdgcn_mfma_f32_16x16x32_f16(a0l, b1h, acc[0][1], 0, 0, 0);
        acc[1][0] = __builtin_amdgcn_mfma_f32_16x16x32_f16(a1l, b0h, acc[1][0], 0, 0, 0);
        acc[1][1] = __builtin_amdgcn_mfma_f32_16x16x32_f16(a1l, b1h, acc[1][1], 0, 0, 0);
    }

    #pragma unroll
    for (int mt = 0; mt < 2; mt++)
        #pragma unroll
        for (int nt = 0; nt < 2; nt++){
            int mb = m0 + wm*32 + mt*16 + quad*4;
            int n  = n0 + wn*32 + nt*16 + l15;
            float bz = bias[n];
            #pragma unroll
            for (int r = 0; r < 4; r++){
                float v = fmaxf(acc[mt][nt][r] + bz, 0.f);
                int m = mb + r;
                if (mode == 0){
                    unsigned short h, l;
                    f32_split(v, h, l);
                    ((unsigned short*)outA)[(size_t)m * N + n] = h;
                    ((unsigned short*)outB)[(size_t)m * N + n] = l;
                } else {
                    ((float*)outA)[(size_t)m * N + n] = v;
                }
            }
        }
}

// ---------------------------------------------------------------------------
// K3: router head. logits = h2 @ rW3 + rb3; softmax (double); top-2 w/ tie->low idx
// block = 256 threads = 32 tokens x 8 experts. grid = MCHUNK/32
// ---------------------------------------------------------------------------
__global__ __launch_bounds__(256) void router_head(
    const float* __restrict__ h2, const float* __restrict__ W3,
    const float* __restrict__ b3, int tokBase,
    int* __restrict__ top2e, float* __restrict__ top2s)
{
    int tid = threadIdx.x;
    int tloc = blockIdx.x * 32 + (tid >> 3);
    int e = tid & 7;
    const float* hrow = h2 + (size_t)tloc * HDIM;
    float acc = 0.f;
    for (int k = 0; k < HDIM; k += 4){
        float4 h = *(const float4*)(hrow + k);
        acc = fmaf(h.x, W3[(k+0)*8 + e], acc);
        acc = fmaf(h.y, W3[(k+1)*8 + e], acc);
        acc = fmaf(h.z, W3[(k+2)*8 + e], acc);
        acc = fmaf(h.w, W3[(k+3)*8 + e], acc);
    }
    float logit = acc + b3[e];
    __shared__ float lg[32][8];
    lg[tid >> 3][e] = logit;
    __syncthreads();
    if (tid < 32){
        double l[8];
        double mx = -1e300;
        for (int i = 0; i < 8; i++){ l[i] = (double)lg[tid][i]; if (l[i] > mx) mx = l[i]; }
        double ex[8]; double s = 0.0;
        for (int i = 0; i < 8; i++){ ex[i] = exp(l[i] - mx); s += ex[i]; }
        double b1v = -1.0, b2v = -1.0; int e1 = 0, e2 = 0;
        for (int i = 0; i < 8; i++){
            double v = ex[i];
            if (v > b1v){ b2v = b1v; e2 = e1; b1v = v; e1 = i; }
            else if (v > b2v){ b2v = v; e2 = i; }
        }
        int gt = tokBase + blockIdx.x * 32 + tid;
        top2e[gt*2 + 0] = e1;
        top2e[gt*2 + 1] = e2;
        top2s[gt*2 + 0] = (float)(b1v / s);
        top2s[gt*2 + 1] = (float)(b2v / s);
    }
}

// ---------------------------------------------------------------------------
// K4: dispatch scan. One block per batch row b. Exact (t, slot) cumsum order.
// ---------------------------------------------------------------------------
__global__ __launch_bounds__(256) void scan_dispatch(
    const int* __restrict__ top2e, int* __restrict__ slot_row, int* __restrict__ row2tok)
{
    int b = blockIdx.x;
    int tid = threadIdx.x;
    __shared__ int cnt[256][8];
    int base = b * (TDIM * 2);
    int i0 = tid * 16;
    int c[8];
    #pragma unroll
    for (int e = 0; e < 8; e++) c[e] = 0;
    for (int j = 0; j < 16; j++){
        int e = top2e[base + i0 + j];
        c[e]++;
    }
    #pragma unroll
    for (int e = 0; e < 8; e++) cnt[tid][e] = c[e];
    __syncthreads();
    if (tid < 8){
        int run = 0;
        for (int t = 0; t < 256; t++){ int v = cnt[t][tid]; cnt[t][tid] = run; run += v; }
    }
    __syncthreads();
    int offs[8];
    #pragma unroll
    for (int e = 0; e < 8; e++) offs[e] = cnt[tid][e];
    for (int j = 0; j < 16; j++){
        int i = i0 + j;
        int e = top2e[base + i];
        int pos = offs[e]++;
        int r = (pos < CAPACITY) ? ((e * BDIM + b) * CAPACITY + pos) : -1;
        slot_row[base + i] = r;
        if (r >= 0) row2tok[r] = b * TDIM + (i >> 1);
    }
}

// ---------------------------------------------------------------------------
// K5: gather tokens into expert slot buffer (bf16). One block per slot row.
// ---------------------------------------------------------------------------
__global__ __launch_bounds__(256) void gather_rows(
    const float* __restrict__ x, const int* __restrict__ row2tok,
    unsigned short* __restrict__ Xe)
{
    int r = blockIdx.x;
    int tid = threadIdx.x;
    int tok = row2tok[r];
    unsigned short* dst = Xe + (size_t)r * CDIM + tid * 4;
    if (tok >= 0){
        float4 v = *(const float4*)(x + (size_t)tok * CDIM + tid * 4);
        ushort4 o;
        o.x = f2bf(v.x); o.y = f2bf(v.y); o.z = f2bf(v.z); o.w = f2bf(v.w);
        *(ushort4*)dst = o;
    } else {
        ushort4 o; o.x = o.y = o.z = o.w = 0;
        *(ushort4*)dst = o;
    }
}

// ---------------------------------------------------------------------------
// K6/K7: bf16 MFMA GEMM.  out = act(A[M,K] @ Bt[N,K]^T + bias[N])
// 64x64 tile, BK=32, 256 threads (4 waves, each 32x32 via 2x2 mfma 16x16x32).
// mode 0: relu -> bf16 out (hidden).  mode 1: plain -> f32 out.
// grid (M/64, N/64)
// ---------------------------------------------------------------------------
__global__ __launch_bounds__(256) void gemm_bf16_mfma(
    const unsigned short* __restrict__ A, const unsigned short* __restrict__ Bt,
    const float* __restrict__ bias, void* __restrict__ outv,
    int M, int N, int K, int mode)
{
    __shared__ unsigned short As[64 * 40];   // [m][k] pad to 40 (80B rows, 16B-aligned)
    __shared__ unsigned short Bs[64 * 40];   // [n][k]
    int tid = threadIdx.x;
    int m0 = blockIdx.x * 64, n0 = blockIdx.y * 64;
    int lane = tid & 63, w = tid >> 6;
    int wm = w & 1, wn = w >> 1;
    int l15 = lane & 15, quad = lane >> 4;

    f32x4 acc[2][2];
    #pragma unroll
    for (int a = 0; a < 2; a++)
        #pragma unroll
        for (int bq = 0; bq < 2; bq++){ acc[a][bq].x=0.f; acc[a][bq].y=0.f; acc[a][bq].z=0.f; acc[a][bq].w=0.f; }

    int srow = tid >> 2, sseg = (tid & 3) * 8;
    const unsigned short* Ap = A + (size_t)(m0 + srow) * K + sseg;
    const unsigned short* Bp = Bt + (size_t)(n0 + srow) * K + sseg;
    unsigned short* Aw = As + srow * 40 + sseg;
    unsigned short* Bw = Bs + srow * 40 + sseg;

    for (int k0 = 0; k0 < K; k0 += 32){
        uint4 av = *(const uint4*)(Ap + k0);
        uint4 bv = *(const uint4*)(Bp + k0);
        __syncthreads();
        *(uint4*)Aw = av;
        *(uint4*)Bw = bv;
        __syncthreads();
        bf16x8 af0 = *(const bf16x8*)(As + (wm*32 +  0 + l15) * 40 + quad*8);
        bf16x8 af1 = *(const bf16x8*)(As + (wm*32 + 16 + l15) * 40 + quad*8);
        bf16x8 bf0 = *(const bf16x8*)(Bs + (wn*32 +  0 + l15) * 40 + quad*8);
        bf16x8 bf1 = *(const bf16x8*)(Bs + (wn*32 + 16 + l15) * 40 + quad*8);
        acc[0][0] = __builtin_amdgcn_mfma_f32_16x16x32_bf16(af0, bf0, acc[0][0], 0, 0, 0);
        acc[0][1] = __builtin_amdgcn_mfma_f32_16x16x32_bf16(af0, bf1, acc[0][1], 0, 0, 0);
        acc[1][0] = __builtin_amdgcn_mfma_f32_16x16x32_bf16(af1, bf0, acc[1][0], 0, 0, 0);
        acc[1][1] = __builtin_amdgcn_mfma_f32_16x16x32_bf16(af1, bf1, acc[1][1], 0, 0, 0);
    }

    #pragma unroll
    for (int mt = 0; mt < 2; mt++)
        #pragma unroll
        for (int nt = 0; nt < 2; nt++){
            int mb = m0 + wm*32 + mt*16 + quad*4;
            int n  = n0 + wn*32 + nt*16 + l15;
            float bz = bias[n];
            #pragma unroll
            for (int r = 0; r < 4; r++){
                float v = acc[mt][nt][r] + bz;
                int m = mb + r;
                if (mode == 0){
                    v = fmaxf(v, 0.f);
                    ((unsigned short*)outv)[(size_t)m * N + n] = f2bf(v);
                } else {
                    ((float*)outv)[(size_t)m * N + n] = v;
                }
            }
        }
}

// ---------------------------------------------------------------------------
// K8: combine. out[b,t,:] = s1*eout[r1,:] + s2*eout[r2,:] (dropped -> 0)
// one block per token
// ---------------------------------------------------------------------------
__global__ __launch_bounds__(256) void combine(
    const float* __restrict__ eout, const int* __restrict__ slot_row,
    const float* __restrict__ top2s, float* __restrict__ out)
{
    int gt = blockIdx.x;
    int b = gt >> 11, t = gt & (TDIM - 1);
    int i = b * (TDIM * 2) + t * 2;
    int r1 = slot_row[i], r2 = slot_row[i + 1];
    float s1 = top2s[gt*2 + 0], s2 = top2s[gt*2 + 1];
    int c = threadIdx.x * 4;
    float4 acc; acc.x = acc.y = acc.z = acc.w = 0.f;
    if (r1 >= 0){
        float4 v = *(const float4*)(eout + (size_t)r1 * CDIM + c);
        acc.x = fmaf(s1, v.x, acc.x); acc.y = fmaf(s1, v.y, acc.y);
        acc.z = fmaf(s1, v.z, acc.z); acc.w = fmaf(s1, v.w, acc.w);
    }
    if (r2 >= 0){
        float4 v = *(const float4*)(eout + (size_t)r2 * CDIM + c);
        acc.x = fmaf(s2, v.x, acc.x); acc.y = fmaf(s2, v.y, acc.y);
        acc.z = fmaf(s2, v.z, acc.z); acc.w = fmaf(s2, v.w, acc.w);
    }
    *(float4*)(out + (size_t)gt * CDIM + c) = acc;
}

// ---------------------------------------------------------------------------
extern "C" void kernel_launch(void* const* d_in, const int* in_sizes, int n_in,
                              void* d_out, int out_size, void* d_ws, size_t ws_size,
                              hipStream_t stream)
{
    const float* x   = (const float*)d_in[0];
    const float* rW1 = (const float*)d_in[1];
    const float* rb1 = (const float*)d_in[2];
    const float* rW2 = (const float*)d_in[3];
    const float* rb2 = (const float*)d_in[4];
    const float* rW3 = (const float*)d_in[5];
    const float* rb3 = (const float*)d_in[6];
    const float* eW1 = (const float*)d_in[7];
    const float* eb1 = (const float*)d_in[8];
    const float* eW2 = (const float*)d_in[9];
    const float* eb2 = (const float*)d_in[10];
    float* out = (float*)d_out;

    // workspace carve-up (all 256B aligned).
    // Persistent region first; then a UNION region reused by the two phases:
    //   phase A (router): Xhi/Xlo, W1t hi/lo, W2t hi/lo, H1 hi/lo, H2      (~218 MB)
    //   phase B (experts): Xe, He, eW1t, eW2t                              (~197 MB)
    char* p = (char*)d_ws;
    auto alloc = [&](size_t bytes) -> void* {
        void* q = (void*)p;
        p += (bytes + 255) & ~(size_t)255;
        return q;
    };
    int*            top2e = (int*)alloc((size_t)MTOK * 2 * 4);
    float*          top2s = (float*)alloc((size_t)MTOK * 2 * 4);
    int*            slotr = (int*)alloc((size_t)BDIM * TDIM * 2 * 4);
    int*            r2tok = (int*)alloc((size_t)NROWS * 4);
    float*          eout  = (float*)alloc((size_t)NROWS * CDIM * 4);           // 84 MB
    char* ubase = p;

    // ---- phase A layout (router) ----
    unsigned short* Xhi   = (unsigned short*)alloc((size_t)MTOK * CDIM * 2);   // 33.5 MB
    unsigned short* Xlo   = (unsigned short*)alloc((size_t)MTOK * CDIM * 2);   // 33.5 MB
    unsigned short* W1thi = (unsigned short*)alloc((size_t)HDIM * CDIM * 2);   // 8.4 MB
    unsigned short* W1tlo = (unsigned short*)alloc((size_t)HDIM * CDIM * 2);   // 8.4 MB
    unsigned short* W2thi = (unsigned short*)alloc((size_t)HDIM * HDIM * 2);   // 33.5 MB
    unsigned short* W2tlo = (unsigned short*)alloc((size_t)HDIM * HDIM * 2);   // 33.5 MB
    unsigned short* H1hi  = (unsigned short*)alloc((size_t)MCHUNK * HDIM * 2); // 16.8 MB
    unsigned short* H1lo  = (unsigned short*)alloc((size_t)MCHUNK * HDIM * 2); // 16.8 MB
    float*          h2c   = (float*)alloc((size_t)MCHUNK * HDIM * 4);          // 33.5 MB

    // ---- phase B layout (experts) — aliases phase A, used only after router done ----
    p = ubase;
    unsigned short* Xe    = (unsigned short*)alloc((size_t)NROWS * CDIM * 2);  // 42 MB
    unsigned short* He    = (unsigned short*)alloc((size_t)EROWS * HDIM * 2);  // 21 MB (per-expert reuse)
    unsigned short* eW1t  = (unsigned short*)alloc((size_t)EDIM * HDIM * CDIM * 2); // 67 MB  [e][H][C]
    unsigned short* eW2t  = (unsigned short*)alloc((size_t)EDIM * CDIM * HDIM * 2); // 67 MB  [e][C][H]

    // 1) router inputs -> exact fp16 hi/lo splits
    split_f16<<<(MTOK * CDIM / 4 + 255) / 256, 256, 0, stream>>>(x, Xhi, Xlo, (size_t)MTOK * CDIM / 4);
    transpose_split<<<dim3(HDIM/32, CDIM/32), 256, 0, stream>>>(rW1, W1thi, W1tlo, CDIM, HDIM);
    transpose_split<<<dim3(HDIM/32, HDIM/32), 256, 0, stream>>>(rW2, W2thi, W2tlo, HDIM, HDIM);

    // 2) router, chunked over tokens (fp16x3 MFMA = fp32-accurate)
    for (int mc = 0; mc < NCHUNKS; mc++){
        const unsigned short* xh = Xhi + (size_t)mc * MCHUNK * CDIM;
        const unsigned short* xl = Xlo + (size_t)mc * MCHUNK * CDIM;
        gemm_f16x3<<<dim3(MCHUNK/64, HDIM/64), 256, 0, stream>>>(
            xh, xl, W1thi, W1tlo, rb1, (void*)H1hi, (void*)H1lo, MCHUNK, HDIM, CDIM, 0);
        gemm_f16x3<<<dim3(MCHUNK/64, HDIM/64), 256, 0, stream>>>(
            H1hi, H1lo, W2thi, W2tlo, rb2, (void*)h2c, nullptr, MCHUNK, HDIM, HDIM, 1);
        router_head<<<MCHUNK/32, 256, 0, stream>>>(h2c, rW3, rb3, mc * MCHUNK, top2e, top2s);
    }

    // 3) dispatch (router phase A buffers dead from here on)
    hipMemsetAsync(r2tok, 0xFF, (size_t)NROWS * 4, stream);
    scan_dispatch<<<BDIM, 256, 0, stream>>>(top2e, slotr, r2tok);
    gather_rows<<<NROWS, 256, 0, stream>>>(x, r2tok, Xe);

    // 4) expert weights -> bf16, transposed to [N][K] (into phase-B union region)
    transpose_convert<<<dim3(HDIM/32, CDIM/32, EDIM), 256, 0, stream>>>(eW1, eW1t, CDIM, HDIM);
    transpose_convert<<<dim3(CDIM/32, HDIM/32, EDIM), 256, 0, stream>>>(eW2, eW2t, HDIM, CDIM);

    // 5) expert FFNs (bf16 MFMA), per-expert to reuse He
    for (int e = 0; e < EDIM; e++){
        const unsigned short* Ae  = Xe   + (size_t)e * EROWS * CDIM;
        const unsigned short* B1  = eW1t + (size_t)e * HDIM * CDIM;
        const unsigned short* B2  = eW2t + (size_t)e * CDIM * HDIM;
        const float*          bz1 = eb1  + (size_t)e * HDIM;
        const float*          bz2 = eb2  + (size_t)e * CDIM;
        float*                Oe  = eout + (size_t)e * EROWS * CDIM;
        gemm_bf16_mfma<<<dim3(EROWS/64, HDIM/64), 256, 0, stream>>>(Ae, B1, bz1, (void*)He, EROWS, HDIM, CDIM, 0);
        gemm_bf16_mfma<<<dim3(EROWS/64, CDIM/64), 256, 0, stream>>>(He, B2, bz2, (void*)Oe, EROWS, CDIM, HDIM, 1);
    }

    // 6) combine
    combine<<<MTOK, 256, 0, stream>>>(eout, slotr, top2s, out);
}

// Round 2
// 4493.484 us; speedup vs baseline: 2.2243x; 1.2441x over previous
//
#include <hip/hip_runtime.h>
#include <hip/hip_bf16.h>

// Problem constants
#define BDIM 8
#define TDIM 2048
#define CDIM 1024
#define HDIM 4096
#define EDIM 8
#define CAPACITY 320
#define MTOK (BDIM*TDIM)          // 16384
#define MCHUNK 2048               // router M-chunk
#define NCHUNKS (MTOK/MCHUNK)     // 8
#define EROWS (BDIM*CAPACITY)     // 2560 rows per expert
#define NROWS (EDIM*EROWS)        // 20480 total slots

typedef __attribute__((ext_vector_type(8))) short bf16x8;
typedef __attribute__((ext_vector_type(8))) _Float16 f16x8;
typedef __attribute__((ext_vector_type(4))) float f32x4;

__device__ __forceinline__ unsigned short f2bf(float f){
    __hip_bfloat16 h = __float2bfloat16(f);
    return *reinterpret_cast<unsigned short*>(&h);
}

// exact 2-term fp16 split: v = hi + lo + O(2^-22 * |v|)
__device__ __forceinline__ void f32_split(float v, unsigned short& h, unsigned short& l){
    _Float16 hh = (_Float16)v;         // RN
    float r = v - (float)hh;           // exact in fp32
    _Float16 ll = (_Float16)r;
    h = __builtin_bit_cast(unsigned short, hh);
    l = __builtin_bit_cast(unsigned short, ll);
}

// async global->LDS, 16B per lane. LDS dest is wave-uniform base + lane*16.
__device__ __forceinline__ void glds16(const unsigned short* g, unsigned short* l){
    __builtin_amdgcn_global_load_lds(
        (const __attribute__((address_space(1))) void*)g,
        (__attribute__((address_space(3))) void*)l,
        16, 0, 0);
}

// ---------------------------------------------------------------------------
// K0: transpose + fp32->bf16 convert.  in: [z][R][Ccol] f32, out: [z][Ccol][R] bf16
// grid: (Ccol/32, R/32, Z), block 256    (expert weights)
// ---------------------------------------------------------------------------
__global__ __launch_bounds__(256) void transpose_convert(
    const float* __restrict__ in, unsigned short* __restrict__ out, int R, int Ccol)
{
    int z = blockIdx.z;
    in  += (size_t)z * R * Ccol;
    out += (size_t)z * R * Ccol;
    __shared__ float tile[32][33];
    int r0 = blockIdx.y * 32, c0 = blockIdx.x * 32;
    int tid = threadIdx.x;
    int lr = tid >> 5, lc = tid & 31;
    #pragma unroll
    for (int it = 0; it < 4; it++)
        tile[it*8 + lr][lc] = in[(size_t)(r0 + it*8 + lr) * Ccol + c0 + lc];
    __syncthreads();
    #pragma unroll
    for (int it = 0; it < 4; it++){
        float v = tile[lc][it*8 + lr];
        out[(size_t)(c0 + it*8 + lr) * R + r0 + lc] = f2bf(v);
    }
}

// ---------------------------------------------------------------------------
// K0b: transpose + fp32 -> fp16 hi/lo split.  in: [R][Ccol] f32, out hi/lo: [Ccol][R]
// grid: (Ccol/32, R/32), block 256    (router weights)
// ---------------------------------------------------------------------------
__global__ __launch_bounds__(256) void transpose_split(
    const float* __restrict__ in, unsigned short* __restrict__ hi,
    unsigned short* __restrict__ lo, int R, int Ccol)
{
    __shared__ float tile[32][33];
    int r0 = blockIdx.y * 32, c0 = blockIdx.x * 32;
    int tid = threadIdx.x;
    int lr = tid >> 5, lc = tid & 31;
    #pragma unroll
    for (int it = 0; it < 4; it++)
        tile[it*8 + lr][lc] = in[(size_t)(r0 + it*8 + lr) * Ccol + c0 + lc];
    __syncthreads();
    #pragma unroll
    for (int it = 0; it < 4; it++){
        float v = tile[lc][it*8 + lr];
        unsigned short h, l;
        f32_split(v, h, l);
        size_t o = (size_t)(c0 + it*8 + lr) * R + r0 + lc;
        hi[o] = h; lo[o] = l;
    }
}

// ---------------------------------------------------------------------------
// K0c: elementwise fp32 -> fp16 hi/lo split (x activations, [M][K] row-major)
// ---------------------------------------------------------------------------
__global__ __launch_bounds__(256) void split_f16(
    const float* __restrict__ in, unsigned short* __restrict__ hi,
    unsigned short* __restrict__ lo, size_t n4)
{
    size_t i = (size_t)blockIdx.x * 256 + threadIdx.x;
    if (i >= n4) return;
    float4 v = ((const float4*)in)[i];
    ushort4 h, l;
    f32_split(v.x, h.x, l.x);
    f32_split(v.y, h.y, l.y);
    f32_split(v.z, h.z, l.z);
    f32_split(v.w, h.w, l.w);
    ((ushort4*)hi)[i] = h;
    ((ushort4*)lo)[i] = l;
}

// ---------------------------------------------------------------------------
// K1/K2: fp32-accurate router GEMM, fp16x3 MFMA, 128x128 tile, BK=32.
// out = relu(A[M,K] @ Bt[N,K]^T + bias[N])
// 256 threads = 4 waves (2x2), each wave owns 64x64 (4x4 frags of 16x16).
// Staging: global_load_lds width=16, LINEAR LDS dest; XOR-swizzle applied on
// the GLOBAL source address and on the ds_read address (both-sides rule):
//   swz(byte) = byte ^ ((row&6)<<3)  within each 64B row  -> 2-way banks (free)
// mode 0: relu -> f16 hi/lo split outputs (outA=hi, outB=lo)
// mode 1: relu -> f32 output (outA)
// grid (M/128, N/128)
// ---------------------------------------------------------------------------
__global__ __launch_bounds__(256) void gemm_f16x3_128(
    const unsigned short* __restrict__ Ahi, const unsigned short* __restrict__ Alo,
    const unsigned short* __restrict__ Bthi, const unsigned short* __restrict__ Btlo,
    const float* __restrict__ bias, void* __restrict__ outA, void* __restrict__ outB,
    int M, int N, int K, int mode)
{
    __shared__ unsigned short AsH[128*32];  // [row][k] linear, 64B rows
    __shared__ unsigned short AsL[128*32];
    __shared__ unsigned short BsH[128*32];
    __shared__ unsigned short BsL[128*32];
    int tid = threadIdx.x;
    int m0 = blockIdx.x * 128, n0 = blockIdx.y * 128;
    int lane = tid & 63, w = tid >> 6;
    int wm = w & 1, wn = w >> 1;
    int l15 = lane & 15, quad = lane >> 4;

    f32x4 acc[4][4];
    #pragma unroll
    for (int i = 0; i < 4; i++)
        #pragma unroll
        for (int j = 0; j < 4; j++){ acc[i][j].x=0.f; acc[i][j].y=0.f; acc[i][j].z=0.f; acc[i][j].w=0.f; }

    // staging: wave w covers rows [w*32, w*32+32) of the 128-row tile, 2 chunks x 16 rows.
    // lane -> row = chunk_row0 + lane/4, dest byte (lane&3)*16 within 64B row;
    // source k-offset carries the inverse swizzle.
    const unsigned short *pAh[2], *pAl[2], *pBh[2], *pBl[2];
    unsigned short *dAh[2], *dAl[2], *dBh[2], *dBl[2];
    #pragma unroll
    for (int i = 0; i < 2; i++){
        int r0  = w*32 + i*16;
        int row = r0 + (lane >> 2);
        int ks  = ((lane & 3) * 8) ^ ((row & 6) << 2);   // shorts
        pAh[i] = Ahi  + (size_t)(m0 + row) * K + ks;
        pAl[i] = Alo  + (size_t)(m0 + row) * K + ks;
        pBh[i] = Bthi + (size_t)(n0 + row) * K + ks;
        pBl[i] = Btlo + (size_t)(n0 + row) * K + ks;
        dAh[i] = AsH + r0*32; dAl[i] = AsL + r0*32;
        dBh[i] = BsH + r0*32; dBl[i] = BsL + r0*32;
    }

    // fragment read byte-offsets (swizzled)
    int roA[4], roB[4];
    #pragma unroll
    for (int t = 0; t < 4; t++){
        int ra = wm*64 + t*16 + l15;
        roA[t] = (ra*64 + quad*16) ^ ((ra & 6) << 3);
        int rb = wn*64 + t*16 + l15;
        roB[t] = (rb*64 + quad*16) ^ ((rb & 6) << 3);
    }

    for (int k0 = 0; k0 < K; k0 += 32){
        __syncthreads();   // previous iteration's LDS reads done
        #pragma unroll
        for (int i = 0; i < 2; i++){
            glds16(pAh[i] + k0, dAh[i]);
            glds16(pAl[i] + k0, dAl[i]);
            glds16(pBh[i] + k0, dBh[i]);
            glds16(pBl[i] + k0, dBl[i]);
        }
        __syncthreads();   // vmcnt drained by barrier semantics -> LDS ready
        f16x8 ah[4], al[4], bh[4], bl[4];
        #pragma unroll
        for (int t = 0; t < 4; t++){
            ah[t] = *(const f16x8*)((const char*)AsH + roA[t]);
            al[t] = *(const f16x8*)((const char*)AsL + roA[t]);
            bh[t] = *(const f16x8*)((const char*)BsH + roB[t]);
            bl[t] = *(const f16x8*)((const char*)BsL + roB[t]);
        }
        #pragma unroll
        for (int mt = 0; mt < 4; mt++)
            #pragma unroll
            for (int nt = 0; nt < 4; nt++){
                acc[mt][nt] = __builtin_amdgcn_mfma_f32_16x16x32_f16(ah[mt], bh[nt], acc[mt][nt], 0, 0, 0);
                acc[mt][nt] = __builtin_amdgcn_mfma_f32_16x16x32_f16(ah[mt], bl[nt], acc[mt][nt], 0, 0, 0);
                acc[mt][nt] = __builtin_amdgcn_mfma_f32_16x16x32_f16(al[mt], bh[nt], acc[mt][nt], 0, 0, 0);
            }
    }

    #pragma unroll
    for (int mt = 0; mt < 4; mt++)
        #pragma unroll
        for (int nt = 0; nt < 4; nt++){
            int mb = m0 + wm*64 + mt*16 + quad*4;
            int n  = n0 + wn*64 + nt*16 + l15;
            float bz = bias[n];
            #pragma unroll
            for (int r = 0; r < 4; r++){
                float v = fmaxf(acc[mt][nt][r] + bz, 0.f);
                int m = mb + r;
                if (mode == 0){
                    unsigned short h, l;
                    f32_split(v, h, l);
                    ((unsigned short*)outA)[(size_t)m * N + n] = h;
                    ((unsigned short*)outB)[(size_t)m * N + n] = l;
                } else {
                    ((float*)outA)[(size_t)m * N + n] = v;
                }
            }
        }
}

// ---------------------------------------------------------------------------
// K6/K7: bf16 MFMA GEMM, 128x128 tile, BK=32, same staging/swizzle structure.
// out = act(A[M,K] @ Bt[N,K]^T + bias[N])
// mode 0: relu -> bf16 out.  mode 1: plain -> f32 out.
// grid (M/128, N/128)
// ---------------------------------------------------------------------------
__global__ __launch_bounds__(256) void gemm_bf16_128(
    const unsigned short* __restrict__ A, const unsigned short* __restrict__ Bt,
    const float* __restrict__ bias, void* __restrict__ outv,
    int M, int N, int K, int mode)
{
    __shared__ unsigned short As[128*32];
    __shared__ unsigned short Bs[128*32];
    int tid = threadIdx.x;
    int m0 = blockIdx.x * 128, n0 = blockIdx.y * 128;
    int lane = tid & 63, w = tid >> 6;
    int wm = w & 1, wn = w >> 1;
    int l15 = lane & 15, quad = lane >> 4;

    f32x4 acc[4][4];
    #pragma unroll
    for (int i = 0; i < 4; i++)
        #pragma unroll
        for (int j = 0; j < 4; j++){ acc[i][j].x=0.f; acc[i][j].y=0.f; acc[i][j].z=0.f; acc[i][j].w=0.f; }

    const unsigned short *pA[2], *pB[2];
    unsigned short *dA[2], *dB[2];
    #pragma unroll
    for (int i = 0; i < 2; i++){
        int r0  = w*32 + i*16;
        int row = r0 + (lane >> 2);
        int ks  = ((lane & 3) * 8) ^ ((row & 6) << 2);
        pA[i] = A  + (size_t)(m0 + row) * K + ks;
        pB[i] = Bt + (size_t)(n0 + row) * K + ks;
        dA[i] = As + r0*32;
        dB[i] = Bs + r0*32;
    }

    int roA[4], roB[4];
    #pragma unroll
    for (int t = 0; t < 4; t++){
        int ra = wm*64 + t*16 + l15;
        roA[t] = (ra*64 + quad*16) ^ ((ra & 6) << 3);
        int rb = wn*64 + t*16 + l15;
        roB[t] = (rb*64 + quad*16) ^ ((rb & 6) << 3);
    }

    for (int k0 = 0; k0 < K; k0 += 32){
        __syncthreads();
        #pragma unroll
        for (int i = 0; i < 2; i++){
            glds16(pA[i] + k0, dA[i]);
            glds16(pB[i] + k0, dB[i]);
        }
        __syncthreads();
        bf16x8 af[4], bf[4];
        #pragma unroll
        for (int t = 0; t < 4; t++){
            af[t] = *(const bf16x8*)((const char*)As + roA[t]);
            bf[t] = *(const bf16x8*)((const char*)Bs + roB[t]);
        }
        #pragma unroll
        for (int mt = 0; mt < 4; mt++)
            #pragma unroll
            for (int nt = 0; nt < 4; nt++)
                acc[mt][nt] = __builtin_amdgcn_mfma_f32_16x16x32_bf16(af[mt], bf[nt], acc[mt][nt], 0, 0, 0);
    }

    #pragma unroll
    for (int mt = 0; mt < 4; mt++)
        #pragma unroll
        for (int nt = 0; nt < 4; nt++){
            int mb = m0 + wm*64 + mt*16 + quad*4;
            int n  = n0 + wn*64 + nt*16 + l15;
            float bz = bias[n];
            #pragma unroll
            for (int r = 0; r < 4; r++){
                float v = acc[mt][nt][r] + bz;
                int m = mb + r;
                if (mode == 0){
                    v = fmaxf(v, 0.f);
                    ((unsigned short*)outv)[(size_t)m * N + n] = f2bf(v);
                } else {
                    ((float*)outv)[(size_t)m * N + n] = v;
                }
            }
        }
}

// ---------------------------------------------------------------------------
// K3: router head. logits = h2 @ rW3 + rb3; softmax (double); top-2 w/ tie->low idx
// block = 256 threads = 32 tokens x 8 experts. grid = MCHUNK/32
// ---------------------------------------------------------------------------
__global__ __launch_bounds__(256) void router_head(
    const float* __restrict__ h2, const float* __restrict__ W3,
    const float* __restrict__ b3, int tokBase,
    int* __restrict__ top2e, float* __restrict__ top2s)
{
    int tid = threadIdx.x;
    int tloc = blockIdx.x * 32 + (tid >> 3);
    int e = tid & 7;
    const float* hrow = h2 + (size_t)tloc * HDIM;
    float acc = 0.f;
    for (int k = 0; k < HDIM; k += 4){
        float4 h = *(const float4*)(hrow + k);
        acc = fmaf(h.x, W3[(k+0)*8 + e], acc);
        acc = fmaf(h.y, W3[(k+1)*8 + e], acc);
        acc = fmaf(h.z, W3[(k+2)*8 + e], acc);
        acc = fmaf(h.w, W3[(k+3)*8 + e], acc);
    }
    float logit = acc + b3[e];
    __shared__ float lg[32][8];
    lg[tid >> 3][e] = logit;
    __syncthreads();
    if (tid < 32){
        double l[8];
        double mx = -1e300;
        for (int i = 0; i < 8; i++){ l[i] = (double)lg[tid][i]; if (l[i] > mx) mx = l[i]; }
        double ex[8]; double s = 0.0;
        for (int i = 0; i < 8; i++){ ex[i] = exp(l[i] - mx); s += ex[i]; }
        double b1v = -1.0, b2v = -1.0; int e1 = 0, e2 = 0;
        for (int i = 0; i < 8; i++){
            double v = ex[i];
            if (v > b1v){ b2v = b1v; e2 = e1; b1v = v; e1 = i; }
            else if (v > b2v){ b2v = v; e2 = i; }
        }
        int gt = tokBase + blockIdx.x * 32 + tid;
        top2e[gt*2 + 0] = e1;
        top2e[gt*2 + 1] = e2;
        top2s[gt*2 + 0] = (float)(b1v / s);
        top2s[gt*2 + 1] = (float)(b2v / s);
    }
}

// ---------------------------------------------------------------------------
// K4: dispatch scan. One block per batch row b. Exact (t, slot) cumsum order.
// ---------------------------------------------------------------------------
__global__ __launch_bounds__(256) void scan_dispatch(
    const int* __restrict__ top2e, int* __restrict__ slot_row, int* __restrict__ row2tok)
{
    int b = blockIdx.x;
    int tid = threadIdx.x;
    __shared__ int cnt[256][8];
    int base = b * (TDIM * 2);
    int i0 = tid * 16;
    int c[8];
    #pragma unroll
    for (int e = 0; e < 8; e++) c[e] = 0;
    for (int j = 0; j < 16; j++){
        int e = top2e[base + i0 + j];
        c[e]++;
    }
    #pragma unroll
    for (int e = 0; e < 8; e++) cnt[tid][e] = c[e];
    __syncthreads();
    if (tid < 8){
        int run = 0;
        for (int t = 0; t < 256; t++){ int v = cnt[t][tid]; cnt[t][tid] = run; run += v; }
    }
    __syncthreads();
    int offs[8];
    #pragma unroll
    for (int e = 0; e < 8; e++) offs[e] = cnt[tid][e];
    for (int j = 0; j < 16; j++){
        int i = i0 + j;
        int e = top2e[base + i];
        int pos = offs[e]++;
        int r = (pos < CAPACITY) ? ((e * BDIM + b) * CAPACITY + pos) : -1;
        slot_row[base + i] = r;
        if (r >= 0) row2tok[r] = b * TDIM + (i >> 1);
    }
}

// ---------------------------------------------------------------------------
// K5: gather tokens into expert slot buffer (bf16). One block per slot row.
// ---------------------------------------------------------------------------
__global__ __launch_bounds__(256) void gather_rows(
    const float* __restrict__ x, const int* __restrict__ row2tok,
    unsigned short* __restrict__ Xe)
{
    int r = blockIdx.x;
    int tid = threadIdx.x;
    int tok = row2tok[r];
    unsigned short* dst = Xe + (size_t)r * CDIM + tid * 4;
    if (tok >= 0){
        float4 v = *(const float4*)(x + (size_t)tok * CDIM + tid * 4);
        ushort4 o;
        o.x = f2bf(v.x); o.y = f2bf(v.y); o.z = f2bf(v.z); o.w = f2bf(v.w);
        *(ushort4*)dst = o;
    } else {
        ushort4 o; o.x = o.y = o.z = o.w = 0;
        *(ushort4*)dst = o;
    }
}

// ---------------------------------------------------------------------------
// K8: combine. out[b,t,:] = s1*eout[r1,:] + s2*eout[r2,:] (dropped -> 0)
// one block per token
// ---------------------------------------------------------------------------
__global__ __launch_bounds__(256) void combine(
    const float* __restrict__ eout, const int* __restrict__ slot_row,
    const float* __restrict__ top2s, float* __restrict__ out)
{
    int gt = blockIdx.x;
    int b = gt >> 11, t = gt & (TDIM - 1);
    int i = b * (TDIM * 2) + t * 2;
    int r1 = slot_row[i], r2 = slot_row[i + 1];
    float s1 = top2s[gt*2 + 0], s2 = top2s[gt*2 + 1];
    int c = threadIdx.x * 4;
    float4 acc; acc.x = acc.y = acc.z = acc.w = 0.f;
    if (r1 >= 0){
        float4 v = *(const float4*)(eout + (size_t)r1 * CDIM + c);
        acc.x = fmaf(s1, v.x, acc.x); acc.y = fmaf(s1, v.y, acc.y);
        acc.z = fmaf(s1, v.z, acc.z); acc.w = fmaf(s1, v.w, acc.w);
    }
    if (r2 >= 0){
        float4 v = *(const float4*)(eout + (size_t)r2 * CDIM + c);
        acc.x = fmaf(s2, v.x, acc.x); acc.y = fmaf(s2, v.y, acc.y);
        acc.z = fmaf(s2, v.z, acc.z); acc.w = fmaf(s2, v.w, acc.w);
    }
    *(float4*)(out + (size_t)gt * CDIM + c) = acc;
}

// ---------------------------------------------------------------------------
extern "C" void kernel_launch(void* const* d_in, const int* in_sizes, int n_in,
                              void* d_out, int out_size, void* d_ws, size_t ws_size,
                              hipStream_t stream)
{
    const float* x   = (const float*)d_in[0];
    const float* rW1 = (const float*)d_in[1];
    const float* rb1 = (const float*)d_in[2];
    const float* rW2 = (const float*)d_in[3];
    const float* rb2 = (const float*)d_in[4];
    const float* rW3 = (const float*)d_in[5];
    const float* rb3 = (const float*)d_in[6];
    const float* eW1 = (const float*)d_in[7];
    const float* eb1 = (const float*)d_in[8];
    const float* eW2 = (const float*)d_in[9];
    const float* eb2 = (const float*)d_in[10];
    float* out = (float*)d_out;

    // workspace carve-up (all 256B aligned).
    // Persistent region first; then a UNION region reused by the two phases:
    //   phase A (router): Xhi/Xlo, W1t hi/lo, W2t hi/lo, H1 hi/lo, H2      (~218 MB)
    //   phase B (experts): Xe, He, eW1t, eW2t                              (~197 MB)
    char* p = (char*)d_ws;
    auto alloc = [&](size_t bytes) -> void* {
        void* q = (void*)p;
        p += (bytes + 255) & ~(size_t)255;
        return q;
    };
    int*            top2e = (int*)alloc((size_t)MTOK * 2 * 4);
    float*          top2s = (float*)alloc((size_t)MTOK * 2 * 4);
    int*            slotr = (int*)alloc((size_t)BDIM * TDIM * 2 * 4);
    int*            r2tok = (int*)alloc((size_t)NROWS * 4);
    float*          eout  = (float*)alloc((size_t)NROWS * CDIM * 4);           // 84 MB
    char* ubase = p;

    // ---- phase A layout (router) ----
    unsigned short* Xhi   = (unsigned short*)alloc((size_t)MTOK * CDIM * 2);   // 33.5 MB
    unsigned short* Xlo   = (unsigned short*)alloc((size_t)MTOK * CDIM * 2);   // 33.5 MB
    unsigned short* W1thi = (unsigned short*)alloc((size_t)HDIM * CDIM * 2);   // 8.4 MB
    unsigned short* W1tlo = (unsigned short*)alloc((size_t)HDIM * CDIM * 2);   // 8.4 MB
    unsigned short* W2thi = (unsigned short*)alloc((size_t)HDIM * HDIM * 2);   // 33.5 MB
    unsigned short* W2tlo = (unsigned short*)alloc((size_t)HDIM * HDIM * 2);   // 33.5 MB
    unsigned short* H1hi  = (unsigned short*)alloc((size_t)MCHUNK * HDIM * 2); // 16.8 MB
    unsigned short* H1lo  = (unsigned short*)alloc((size_t)MCHUNK * HDIM * 2); // 16.8 MB
    float*          h2c   = (float*)alloc((size_t)MCHUNK * HDIM * 4);          // 33.5 MB

    // ---- phase B layout (experts) — aliases phase A, used only after router done ----
    p = ubase;
    unsigned short* Xe    = (unsigned short*)alloc((size_t)NROWS * CDIM * 2);  // 42 MB
    unsigned short* He    = (unsigned short*)alloc((size_t)EROWS * HDIM * 2);  // 21 MB (per-expert reuse)
    unsigned short* eW1t  = (unsigned short*)alloc((size_t)EDIM * HDIM * CDIM * 2); // 67 MB  [e][H][C]
    unsigned short* eW2t  = (unsigned short*)alloc((size_t)EDIM * CDIM * HDIM * 2); // 67 MB  [e][C][H]

    // 1) router inputs -> exact fp16 hi/lo splits
    split_f16<<<(MTOK * CDIM / 4 + 255) / 256, 256, 0, stream>>>(x, Xhi, Xlo, (size_t)MTOK * CDIM / 4);
    transpose_split<<<dim3(HDIM/32, CDIM/32), 256, 0, stream>>>(rW1, W1thi, W1tlo, CDIM, HDIM);
    transpose_split<<<dim3(HDIM/32, HDIM/32), 256, 0, stream>>>(rW2, W2thi, W2tlo, HDIM, HDIM);

    // 2) router, chunked over tokens (fp16x3 MFMA = fp32-accurate)
    for (int mc = 0; mc < NCHUNKS; mc++){
        const unsigned short* xh = Xhi + (size_t)mc * MCHUNK * CDIM;
        const unsigned short* xl = Xlo + (size_t)mc * MCHUNK * CDIM;
        gemm_f16x3_128<<<dim3(MCHUNK/128, HDIM/128), 256, 0, stream>>>(
            xh, xl, W1thi, W1tlo, rb1, (void*)H1hi, (void*)H1lo, MCHUNK, HDIM, CDIM, 0);
        gemm_f16x3_128<<<dim3(MCHUNK/128, HDIM/128), 256, 0, stream>>>(
            H1hi, H1lo, W2thi, W2tlo, rb2, (void*)h2c, nullptr, MCHUNK, HDIM, HDIM, 1);
        router_head<<<MCHUNK/32, 256, 0, stream>>>(h2c, rW3, rb3, mc * MCHUNK, top2e, top2s);
    }

    // 3) dispatch (router phase A buffers dead from here on)
    hipMemsetAsync(r2tok, 0xFF, (size_t)NROWS * 4, stream);
    scan_dispatch<<<BDIM, 256, 0, stream>>>(top2e, slotr, r2tok);
    gather_rows<<<NROWS, 256, 0, stream>>>(x, r2tok, Xe);

    // 4) expert weights -> bf16, transposed to [N][K] (into phase-B union region)
    transpose_convert<<<dim3(HDIM/32, CDIM/32, EDIM), 256, 0, stream>>>(eW1, eW1t, CDIM, HDIM);
    transpose_convert<<<dim3(CDIM/32, HDIM/32, EDIM), 256, 0, stream>>>(eW2, eW2t, HDIM, CDIM);

    // 5) expert FFNs (bf16 MFMA), per-expert to reuse He
    for (int e = 0; e < EDIM; e++){
        const unsigned short* Ae  = Xe   + (size_t)e * EROWS * CDIM;
        const unsigned short* B1  = eW1t + (size_t)e * HDIM * CDIM;
        const unsigned short* B2  = eW2t + (size_t)e * CDIM * HDIM;
        const float*          bz1 = eb1  + (size_t)e * HDIM;
        const float*          bz2 = eb2  + (size_t)e * CDIM;
        float*                Oe  = eout + (size_t)e * EROWS * CDIM;
        gemm_bf16_128<<<dim3(EROWS/128, HDIM/128), 256, 0, stream>>>(Ae, B1, bz1, (void*)He, EROWS, HDIM, CDIM, 0);
        gemm_bf16_128<<<dim3(EROWS/128, CDIM/128), 256, 0, stream>>>(He, B2, bz2, (void*)Oe, EROWS, CDIM, HDIM, 1);
    }

    // 6) combine
    combine<<<MTOK, 256, 0, stream>>>(eout, slotr, top2s, out);
}

// Round 4
// 4051.071 us; speedup vs baseline: 2.4672x; 1.1092x over previous
//
#include <hip/hip_runtime.h>
#include <hip/hip_bf16.h>

// Problem constants
#define BDIM 8
#define TDIM 2048
#define CDIM 1024
#define HDIM 4096
#define EDIM 8
#define CAPACITY 320
#define MTOK (BDIM*TDIM)          // 16384
#define MCHUNK 2048               // router M-chunk (2048 -> proven 303 MB workspace)
#define NCHUNKS (MTOK/MCHUNK)     // 8
#define EROWS (BDIM*CAPACITY)     // 2560 rows per expert
#define NROWS (EDIM*EROWS)        // 20480 total slots

typedef __attribute__((ext_vector_type(8))) short bf16x8;
typedef __attribute__((ext_vector_type(8))) _Float16 f16x8;
typedef __attribute__((ext_vector_type(4))) float f32x4;

__device__ __forceinline__ unsigned short f2bf(float f){
    __hip_bfloat16 h = __float2bfloat16(f);
    return *reinterpret_cast<unsigned short*>(&h);
}

// exact 2-term fp16 split: v = hi + lo + O(2^-22 * |v|)
__device__ __forceinline__ void f32_split(float v, unsigned short& h, unsigned short& l){
    _Float16 hh = (_Float16)v;         // RN
    float r = v - (float)hh;           // exact in fp32
    _Float16 ll = (_Float16)r;
    h = __builtin_bit_cast(unsigned short, hh);
    l = __builtin_bit_cast(unsigned short, ll);
}

// async global->LDS, 16B per lane. LDS dest is wave-uniform base + lane*16.
__device__ __forceinline__ void glds16(const unsigned short* g, unsigned short* l){
    __builtin_amdgcn_global_load_lds(
        (const __attribute__((address_space(1))) void*)g,
        (__attribute__((address_space(3))) void*)l,
        16, 0, 0);
}

// XCD-aware bijective block swizzle (requires nwg % 8 == 0, else identity).
__device__ __forceinline__ void xcd_tile(int& bx, int& by){
    int nbx = gridDim.x, nby = gridDim.y;
    int nwg = nbx * nby;
    int orig = blockIdx.y * nbx + blockIdx.x;
    int wg = orig;
    if ((nwg & 7) == 0){
        int cpx = nwg >> 3;
        wg = (orig & 7) * cpx + (orig >> 3);
    }
    bx = wg % nbx;
    by = wg / nbx;
}

// ---------------------------------------------------------------------------
// K0: transpose + fp32->bf16 convert.  in: [z][R][Ccol] f32, out: [z][Ccol][R] bf16
// grid: (Ccol/32, R/32, Z), block 256    (expert weights)
// ---------------------------------------------------------------------------
__global__ __launch_bounds__(256) void transpose_convert(
    const float* __restrict__ in, unsigned short* __restrict__ out, int R, int Ccol)
{
    int z = blockIdx.z;
    in  += (size_t)z * R * Ccol;
    out += (size_t)z * R * Ccol;
    __shared__ float tile[32][33];
    int r0 = blockIdx.y * 32, c0 = blockIdx.x * 32;
    int tid = threadIdx.x;
    int lr = tid >> 5, lc = tid & 31;
    #pragma unroll
    for (int it = 0; it < 4; it++)
        tile[it*8 + lr][lc] = in[(size_t)(r0 + it*8 + lr) * Ccol + c0 + lc];
    __syncthreads();
    #pragma unroll
    for (int it = 0; it < 4; it++){
        float v = tile[lc][it*8 + lr];
        out[(size_t)(c0 + it*8 + lr) * R + r0 + lc] = f2bf(v);
    }
}

// ---------------------------------------------------------------------------
// K0b: transpose + fp32 -> fp16 hi/lo split.  in: [R][Ccol] f32, out hi/lo: [Ccol][R]
// grid: (Ccol/32, R/32), block 256    (router weights)
// ---------------------------------------------------------------------------
__global__ __launch_bounds__(256) void transpose_split(
    const float* __restrict__ in, unsigned short* __restrict__ hi,
    unsigned short* __restrict__ lo, int R, int Ccol)
{
    __shared__ float tile[32][33];
    int r0 = blockIdx.y * 32, c0 = blockIdx.x * 32;
    int tid = threadIdx.x;
    int lr = tid >> 5, lc = tid & 31;
    #pragma unroll
    for (int it = 0; it < 4; it++)
        tile[it*8 + lr][lc] = in[(size_t)(r0 + it*8 + lr) * Ccol + c0 + lc];
    __syncthreads();
    #pragma unroll
    for (int it = 0; it < 4; it++){
        float v = tile[lc][it*8 + lr];
        unsigned short h, l;
        f32_split(v, h, l);
        size_t o = (size_t)(c0 + it*8 + lr) * R + r0 + lc;
        hi[o] = h; lo[o] = l;
    }
}

// ---------------------------------------------------------------------------
// K0c: elementwise fp32 -> fp16 hi/lo split (x activations, [M][K] row-major)
// ---------------------------------------------------------------------------
__global__ __launch_bounds__(256) void split_f16(
    const float* __restrict__ in, unsigned short* __restrict__ hi,
    unsigned short* __restrict__ lo, size_t n4)
{
    size_t i = (size_t)blockIdx.x * 256 + threadIdx.x;
    if (i >= n4) return;
    float4 v = ((const float4*)in)[i];
    ushort4 h, l;
    f32_split(v.x, h.x, l.x);
    f32_split(v.y, h.y, l.y);
    f32_split(v.z, h.z, l.z);
    f32_split(v.w, h.w, l.w);
    ((ushort4*)hi)[i] = h;
    ((ushort4*)lo)[i] = l;
}

// ---------------------------------------------------------------------------
// K1/K2: fp32-accurate router GEMM, fp16x3 MFMA, 128x128 tile, BK=32,
// DOUBLE-BUFFERED LDS (T3 minimum 2-phase): issue next K-tile's
// global_load_lds BEFORE computing current tile; single barrier per K-step.
// The compiler-implicit vmcnt(0)+lgkmcnt(0) drain at __syncthreads is the
// correctness sync; prefetch latency overlaps the 48-MFMA compute phase.
// XOR-swizzle (both-sides rule): swz(byte) = byte ^ ((row&6)<<3) in 64B rows.
// mode 0: relu -> f16 hi/lo split outputs (outA=hi, outB=lo)
// mode 1: relu -> f32 output (outA)
// grid (M/128, N/128)
// ---------------------------------------------------------------------------
__global__ __launch_bounds__(256) void gemm_f16x3_128(
    const unsigned short* __restrict__ Ahi, const unsigned short* __restrict__ Alo,
    const unsigned short* __restrict__ Bthi, const unsigned short* __restrict__ Btlo,
    const float* __restrict__ bias, void* __restrict__ outA, void* __restrict__ outB,
    int M, int N, int K, int mode)
{
    __shared__ unsigned short AsH[2][128*32];  // [buf][row][k] linear, 64B rows
    __shared__ unsigned short AsL[2][128*32];
    __shared__ unsigned short BsH[2][128*32];
    __shared__ unsigned short BsL[2][128*32];
    int tid = threadIdx.x;
    int bx, by; xcd_tile(bx, by);
    int m0 = bx * 128, n0 = by * 128;
    int lane = tid & 63, w = tid >> 6;
    int wm = w & 1, wn = w >> 1;
    int l15 = lane & 15, quad = lane >> 4;

    f32x4 acc[4][4];
    #pragma unroll
    for (int i = 0; i < 4; i++)
        #pragma unroll
        for (int j = 0; j < 4; j++){ acc[i][j].x=0.f; acc[i][j].y=0.f; acc[i][j].z=0.f; acc[i][j].w=0.f; }

    // staging: wave w covers rows [w*32, w*32+32), 2 chunks x 16 rows.
    // lane -> row = chunk_row0 + lane/4, dest byte (lane&3)*16 within 64B row;
    // source k-offset carries the inverse swizzle.
    const unsigned short *pAh[2], *pAl[2], *pBh[2], *pBl[2];
    int wo[2];
    #pragma unroll
    for (int i = 0; i < 2; i++){
        int r0  = w*32 + i*16;
        int row = r0 + (lane >> 2);
        int ks  = ((lane & 3) * 8) ^ ((row & 6) << 2);   // shorts
        pAh[i] = Ahi  + (size_t)(m0 + row) * K + ks;
        pAl[i] = Alo  + (size_t)(m0 + row) * K + ks;
        pBh[i] = Bthi + (size_t)(n0 + row) * K + ks;
        pBl[i] = Btlo + (size_t)(n0 + row) * K + ks;
        wo[i]  = r0 * 32;
    }

    // fragment read byte-offsets (swizzled)
    int roA[4], roB[4];
    #pragma unroll
    for (int t = 0; t < 4; t++){
        int ra = wm*64 + t*16 + l15;
        roA[t] = (ra*64 + quad*16) ^ ((ra & 6) << 3);
        int rb = wn*64 + t*16 + l15;
        roB[t] = (rb*64 + quad*16) ^ ((rb & 6) << 3);
    }

    // prologue: stage K-tile 0 into buffer 0
    #pragma unroll
    for (int i = 0; i < 2; i++){
        glds16(pAh[i], &AsH[0][wo[i]]);
        glds16(pAl[i], &AsL[0][wo[i]]);
        glds16(pBh[i], &BsH[0][wo[i]]);
        glds16(pBl[i], &BsL[0][wo[i]]);
    }
    __syncthreads();

    int nt = K >> 5;
    int cur = 0;
    for (int t = 0; t < nt; t++){
        if (t + 1 < nt){
            int ko = (t + 1) * 32;
            #pragma unroll
            for (int i = 0; i < 2; i++){
                glds16(pAh[i] + ko, &AsH[cur^1][wo[i]]);
                glds16(pAl[i] + ko, &AsL[cur^1][wo[i]]);
                glds16(pBh[i] + ko, &BsH[cur^1][wo[i]]);
                glds16(pBl[i] + ko, &BsL[cur^1][wo[i]]);
            }
        }
        f16x8 ah[4], al[4], bh[4], bl[4];
        #pragma unroll
        for (int t4 = 0; t4 < 4; t4++){
            ah[t4] = *(const f16x8*)((const char*)AsH[cur] + roA[t4]);
            al[t4] = *(const f16x8*)((const char*)AsL[cur] + roA[t4]);
            bh[t4] = *(const f16x8*)((const char*)BsH[cur] + roB[t4]);
            bl[t4] = *(const f16x8*)((const char*)BsL[cur] + roB[t4]);
        }
        __builtin_amdgcn_s_setprio(1);
        #pragma unroll
        for (int mt = 0; mt < 4; mt++)
            #pragma unroll
            for (int nt2 = 0; nt2 < 4; nt2++){
                acc[mt][nt2] = __builtin_amdgcn_mfma_f32_16x16x32_f16(ah[mt], bh[nt2], acc[mt][nt2], 0, 0, 0);
                acc[mt][nt2] = __builtin_amdgcn_mfma_f32_16x16x32_f16(ah[mt], bl[nt2], acc[mt][nt2], 0, 0, 0);
                acc[mt][nt2] = __builtin_amdgcn_mfma_f32_16x16x32_f16(al[mt], bh[nt2], acc[mt][nt2], 0, 0, 0);
            }
        __builtin_amdgcn_s_setprio(0);
        __syncthreads();
        cur ^= 1;
    }

    #pragma unroll
    for (int mt = 0; mt < 4; mt++)
        #pragma unroll
        for (int nt2 = 0; nt2 < 4; nt2++){
            int mb = m0 + wm*64 + mt*16 + quad*4;
            int n  = n0 + wn*64 + nt2*16 + l15;
            float bz = bias[n];
            #pragma unroll
            for (int r = 0; r < 4; r++){
                float v = fmaxf(acc[mt][nt2][r] + bz, 0.f);
                int m = mb + r;
                if (mode == 0){
                    unsigned short h, l;
                    f32_split(v, h, l);
                    ((unsigned short*)outA)[(size_t)m * N + n] = h;
                    ((unsigned short*)outB)[(size_t)m * N + n] = l;
                } else {
                    ((float*)outA)[(size_t)m * N + n] = v;
                }
            }
        }
}

// ---------------------------------------------------------------------------
// K6/K7: bf16 MFMA GEMM, 128x128 tile, BK=32, same dbuf/swizzle structure.
// out = act(A[M,K] @ Bt[N,K]^T + bias[N])
// mode 0: relu -> bf16 out.  mode 1: plain -> f32 out.
// grid (M/128, N/128)
// ---------------------------------------------------------------------------
__global__ __launch_bounds__(256) void gemm_bf16_128(
    const unsigned short* __restrict__ A, const unsigned short* __restrict__ Bt,
    const float* __restrict__ bias, void* __restrict__ outv,
    int M, int N, int K, int mode)
{
    __shared__ unsigned short As[2][128*32];
    __shared__ unsigned short Bs[2][128*32];
    int tid = threadIdx.x;
    int bx, by; xcd_tile(bx, by);
    int m0 = bx * 128, n0 = by * 128;
    int lane = tid & 63, w = tid >> 6;
    int wm = w & 1, wn = w >> 1;
    int l15 = lane & 15, quad = lane >> 4;

    f32x4 acc[4][4];
    #pragma unroll
    for (int i = 0; i < 4; i++)
        #pragma unroll
        for (int j = 0; j < 4; j++){ acc[i][j].x=0.f; acc[i][j].y=0.f; acc[i][j].z=0.f; acc[i][j].w=0.f; }

    const unsigned short *pA[2], *pB[2];
    int wo[2];
    #pragma unroll
    for (int i = 0; i < 2; i++){
        int r0  = w*32 + i*16;
        int row = r0 + (lane >> 2);
        int ks  = ((lane & 3) * 8) ^ ((row & 6) << 2);
        pA[i] = A  + (size_t)(m0 + row) * K + ks;
        pB[i] = Bt + (size_t)(n0 + row) * K + ks;
        wo[i] = r0 * 32;
    }

    int roA[4], roB[4];
    #pragma unroll
    for (int t = 0; t < 4; t++){
        int ra = wm*64 + t*16 + l15;
        roA[t] = (ra*64 + quad*16) ^ ((ra & 6) << 3);
        int rb = wn*64 + t*16 + l15;
        roB[t] = (rb*64 + quad*16) ^ ((rb & 6) << 3);
    }

    #pragma unroll
    for (int i = 0; i < 2; i++){
        glds16(pA[i], &As[0][wo[i]]);
        glds16(pB[i], &Bs[0][wo[i]]);
    }
    __syncthreads();

    int nt = K >> 5;
    int cur = 0;
    for (int t = 0; t < nt; t++){
        if (t + 1 < nt){
            int ko = (t + 1) * 32;
            #pragma unroll
            for (int i = 0; i < 2; i++){
                glds16(pA[i] + ko, &As[cur^1][wo[i]]);
                glds16(pB[i] + ko, &Bs[cur^1][wo[i]]);
            }
        }
        bf16x8 af[4], bf[4];
        #pragma unroll
        for (int t4 = 0; t4 < 4; t4++){
            af[t4] = *(const bf16x8*)((const char*)As[cur] + roA[t4]);
            bf[t4] = *(const bf16x8*)((const char*)Bs[cur] + roB[t4]);
        }
        __builtin_amdgcn_s_setprio(1);
        #pragma unroll
        for (int mt = 0; mt < 4; mt++)
            #pragma unroll
            for (int nt2 = 0; nt2 < 4; nt2++)
                acc[mt][nt2] = __builtin_amdgcn_mfma_f32_16x16x32_bf16(af[mt], bf[nt2], acc[mt][nt2], 0, 0, 0);
        __builtin_amdgcn_s_setprio(0);
        __syncthreads();
        cur ^= 1;
    }

    #pragma unroll
    for (int mt = 0; mt < 4; mt++)
        #pragma unroll
        for (int nt2 = 0; nt2 < 4; nt2++){
            int mb = m0 + wm*64 + mt*16 + quad*4;
            int n  = n0 + wn*64 + nt2*16 + l15;
            float bz = bias[n];
            #pragma unroll
            for (int r = 0; r < 4; r++){
                float v = acc[mt][nt2][r] + bz;
                int m = mb + r;
                if (mode == 0){
                    v = fmaxf(v, 0.f);
                    ((unsigned short*)outv)[(size_t)m * N + n] = f2bf(v);
                } else {
                    ((float*)outv)[(size_t)m * N + n] = v;
                }
            }
        }
}

// ---------------------------------------------------------------------------
// K3: router head. logits = h2 @ rW3 + rb3; softmax (double); top-2 w/ tie->low idx
// block = 256 threads = 32 tokens x 8 experts. grid = MCHUNK/32
// ---------------------------------------------------------------------------
__global__ __launch_bounds__(256) void router_head(
    const float* __restrict__ h2, const float* __restrict__ W3,
    const float* __restrict__ b3, int tokBase,
    int* __restrict__ top2e, float* __restrict__ top2s)
{
    int tid = threadIdx.x;
    int tloc = blockIdx.x * 32 + (tid >> 3);
    int e = tid & 7;
    const float* hrow = h2 + (size_t)tloc * HDIM;
    float acc = 0.f;
    for (int k = 0; k < HDIM; k += 4){
        float4 h = *(const float4*)(hrow + k);
        acc = fmaf(h.x, W3[(k+0)*8 + e], acc);
        acc = fmaf(h.y, W3[(k+1)*8 + e], acc);
        acc = fmaf(h.z, W3[(k+2)*8 + e], acc);
        acc = fmaf(h.w, W3[(k+3)*8 + e], acc);
    }
    float logit = acc + b3[e];
    __shared__ float lg[32][8];
    lg[tid >> 3][e] = logit;
    __syncthreads();
    if (tid < 32){
        double l[8];
        double mx = -1e300;
        for (int i = 0; i < 8; i++){ l[i] = (double)lg[tid][i]; if (l[i] > mx) mx = l[i]; }
        double ex[8]; double s = 0.0;
        for (int i = 0; i < 8; i++){ ex[i] = exp(l[i] - mx); s += ex[i]; }
        double b1v = -1.0, b2v = -1.0; int e1 = 0, e2 = 0;
        for (int i = 0; i < 8; i++){
            double v = ex[i];
            if (v > b1v){ b2v = b1v; e2 = e1; b1v = v; e1 = i; }
            else if (v > b2v){ b2v = v; e2 = i; }
        }
        int gt = tokBase + blockIdx.x * 32 + tid;
        top2e[gt*2 + 0] = e1;
        top2e[gt*2 + 1] = e2;
        top2s[gt*2 + 0] = (float)(b1v / s);
        top2s[gt*2 + 1] = (float)(b2v / s);
    }
}

// ---------------------------------------------------------------------------
// K4: dispatch scan. One block per batch row b. Exact (t, slot) cumsum order.
// ---------------------------------------------------------------------------
__global__ __launch_bounds__(256) void scan_dispatch(
    const int* __restrict__ top2e, int* __restrict__ slot_row, int* __restrict__ row2tok)
{
    int b = blockIdx.x;
    int tid = threadIdx.x;
    __shared__ int cnt[256][8];
    int base = b * (TDIM * 2);
    int i0 = tid * 16;
    int c[8];
    #pragma unroll
    for (int e = 0; e < 8; e++) c[e] = 0;
    for (int j = 0; j < 16; j++){
        int e = top2e[base + i0 + j];
        c[e]++;
    }
    #pragma unroll
    for (int e = 0; e < 8; e++) cnt[tid][e] = c[e];
    __syncthreads();
    if (tid < 8){
        int run = 0;
        for (int t = 0; t < 256; t++){ int v = cnt[t][tid]; cnt[t][tid] = run; run += v; }
    }
    __syncthreads();
    int offs[8];
    #pragma unroll
    for (int e = 0; e < 8; e++) offs[e] = cnt[tid][e];
    for (int j = 0; j < 16; j++){
        int i = i0 + j;
        int e = top2e[base + i];
        int pos = offs[e]++;
        int r = (pos < CAPACITY) ? ((e * BDIM + b) * CAPACITY + pos) : -1;
        slot_row[base + i] = r;
        if (r >= 0) row2tok[r] = b * TDIM + (i >> 1);
    }
}

// ---------------------------------------------------------------------------
// K5: gather tokens into expert slot buffer (bf16). One block per slot row.
// ---------------------------------------------------------------------------
__global__ __launch_bounds__(256) void gather_rows(
    const float* __restrict__ x, const int* __restrict__ row2tok,
    unsigned short* __restrict__ Xe)
{
    int r = blockIdx.x;
    int tid = threadIdx.x;
    int tok = row2tok[r];
    unsigned short* dst = Xe + (size_t)r * CDIM + tid * 4;
    if (tok >= 0){
        float4 v = *(const float4*)(x + (size_t)tok * CDIM + tid * 4);
        ushort4 o;
        o.x = f2bf(v.x); o.y = f2bf(v.y); o.z = f2bf(v.z); o.w = f2bf(v.w);
        *(ushort4*)dst = o;
    } else {
        ushort4 o; o.x = o.y = o.z = o.w = 0;
        *(ushort4*)dst = o;
    }
}

// ---------------------------------------------------------------------------
// K8: combine. out[b,t,:] = s1*eout[r1,:] + s2*eout[r2,:] (dropped -> 0)
// one block per token
// ---------------------------------------------------------------------------
__global__ __launch_bounds__(256) void combine(
    const float* __restrict__ eout, const int* __restrict__ slot_row,
    const float* __restrict__ top2s, float* __restrict__ out)
{
    int gt = blockIdx.x;
    int b = gt >> 11, t = gt & (TDIM - 1);
    int i = b * (TDIM * 2) + t * 2;
    int r1 = slot_row[i], r2 = slot_row[i + 1];
    float s1 = top2s[gt*2 + 0], s2 = top2s[gt*2 + 1];
    int c = threadIdx.x * 4;
    float4 acc; acc.x = acc.y = acc.z = acc.w = 0.f;
    if (r1 >= 0){
        float4 v = *(const float4*)(eout + (size_t)r1 * CDIM + c);
        acc.x = fmaf(s1, v.x, acc.x); acc.y = fmaf(s1, v.y, acc.y);
        acc.z = fmaf(s1, v.z, acc.z); acc.w = fmaf(s1, v.w, acc.w);
    }
    if (r2 >= 0){
        float4 v = *(const float4*)(eout + (size_t)r2 * CDIM + c);
        acc.x = fmaf(s2, v.x, acc.x); acc.y = fmaf(s2, v.y, acc.y);
        acc.z = fmaf(s2, v.z, acc.z); acc.w = fmaf(s2, v.w, acc.w);
    }
    *(float4*)(out + (size_t)gt * CDIM + c) = acc;
}

// ---------------------------------------------------------------------------
extern "C" void kernel_launch(void* const* d_in, const int* in_sizes, int n_in,
                              void* d_out, int out_size, void* d_ws, size_t ws_size,
                              hipStream_t stream)
{
    const float* x   = (const float*)d_in[0];
    const float* rW1 = (const float*)d_in[1];
    const float* rb1 = (const float*)d_in[2];
    const float* rW2 = (const float*)d_in[3];
    const float* rb2 = (const float*)d_in[4];
    const float* rW3 = (const float*)d_in[5];
    const float* rb3 = (const float*)d_in[6];
    const float* eW1 = (const float*)d_in[7];
    const float* eb1 = (const float*)d_in[8];
    const float* eW2 = (const float*)d_in[9];
    const float* eb2 = (const float*)d_in[10];
    float* out = (float*)d_out;

    // workspace carve-up (all 256B aligned).
    // Persistent (~85 MB) + UNION region reused by the two phases:
    //   phase A (router, MCHUNK=2048): ~218 MB   -> total ~303 MB (proven in r1/r2)
    //   phase B (experts): ~197 MB
    char* p = (char*)d_ws;
    auto alloc = [&](size_t bytes) -> void* {
        void* q = (void*)p;
        p += (bytes + 255) & ~(size_t)255;
        return q;
    };
    int*            top2e = (int*)alloc((size_t)MTOK * 2 * 4);
    float*          top2s = (float*)alloc((size_t)MTOK * 2 * 4);
    int*            slotr = (int*)alloc((size_t)BDIM * TDIM * 2 * 4);
    int*            r2tok = (int*)alloc((size_t)NROWS * 4);
    float*          eout  = (float*)alloc((size_t)NROWS * CDIM * 4);           // 84 MB
    char* ubase = p;

    // ---- phase A layout (router) ----
    unsigned short* Xhi   = (unsigned short*)alloc((size_t)MTOK * CDIM * 2);   // 33.5 MB
    unsigned short* Xlo   = (unsigned short*)alloc((size_t)MTOK * CDIM * 2);   // 33.5 MB
    unsigned short* W1thi = (unsigned short*)alloc((size_t)HDIM * CDIM * 2);   // 8.4 MB
    unsigned short* W1tlo = (unsigned short*)alloc((size_t)HDIM * CDIM * 2);   // 8.4 MB
    unsigned short* W2thi = (unsigned short*)alloc((size_t)HDIM * HDIM * 2);   // 33.5 MB
    unsigned short* W2tlo = (unsigned short*)alloc((size_t)HDIM * HDIM * 2);   // 33.5 MB
    unsigned short* H1hi  = (unsigned short*)alloc((size_t)MCHUNK * HDIM * 2); // 16.8 MB
    unsigned short* H1lo  = (unsigned short*)alloc((size_t)MCHUNK * HDIM * 2); // 16.8 MB
    float*          h2c   = (float*)alloc((size_t)MCHUNK * HDIM * 4);          // 33.5 MB

    // ---- phase B layout (experts) — aliases phase A, used only after router done ----
    p = ubase;
    unsigned short* Xe    = (unsigned short*)alloc((size_t)NROWS * CDIM * 2);  // 42 MB
    unsigned short* He    = (unsigned short*)alloc((size_t)EROWS * HDIM * 2);  // 21 MB (per-expert reuse)
    unsigned short* eW1t  = (unsigned short*)alloc((size_t)EDIM * HDIM * CDIM * 2); // 67 MB  [e][H][C]
    unsigned short* eW2t  = (unsigned short*)alloc((size_t)EDIM * CDIM * HDIM * 2); // 67 MB  [e][C][H]

    // 1) router inputs -> exact fp16 hi/lo splits
    split_f16<<<(MTOK * CDIM / 4 + 255) / 256, 256, 0, stream>>>(x, Xhi, Xlo, (size_t)MTOK * CDIM / 4);
    transpose_split<<<dim3(HDIM/32, CDIM/32), 256, 0, stream>>>(rW1, W1thi, W1tlo, CDIM, HDIM);
    transpose_split<<<dim3(HDIM/32, HDIM/32), 256, 0, stream>>>(rW2, W2thi, W2tlo, HDIM, HDIM);

    // 2) router, chunked over tokens (fp16x3 MFMA = fp32-accurate)
    for (int mc = 0; mc < NCHUNKS; mc++){
        const unsigned short* xh = Xhi + (size_t)mc * MCHUNK * CDIM;
        const unsigned short* xl = Xlo + (size_t)mc * MCHUNK * CDIM;
        gemm_f16x3_128<<<dim3(MCHUNK/128, HDIM/128), 256, 0, stream>>>(
            xh, xl, W1thi, W1tlo, rb1, (void*)H1hi, (void*)H1lo, MCHUNK, HDIM, CDIM, 0);
        gemm_f16x3_128<<<dim3(MCHUNK/128, HDIM/128), 256, 0, stream>>>(
            H1hi, H1lo, W2thi, W2tlo, rb2, (void*)h2c, nullptr, MCHUNK, HDIM, HDIM, 1);
        router_head<<<MCHUNK/32, 256, 0, stream>>>(h2c, rW3, rb3, mc * MCHUNK, top2e, top2s);
    }

    // 3) dispatch (router phase A buffers dead from here on)
    hipMemsetAsync(r2tok, 0xFF, (size_t)NROWS * 4, stream);
    scan_dispatch<<<BDIM, 256, 0, stream>>>(top2e, slotr, r2tok);
    gather_rows<<<NROWS, 256, 0, stream>>>(x, r2tok, Xe);

    // 4) expert weights -> bf16, transposed to [N][K] (into phase-B union region)
    transpose_convert<<<dim3(HDIM/32, CDIM/32, EDIM), 256, 0, stream>>>(eW1, eW1t, CDIM, HDIM);
    transpose_convert<<<dim3(CDIM/32, HDIM/32, EDIM), 256, 0, stream>>>(eW2, eW2t, HDIM, CDIM);

    // 5) expert FFNs (bf16 MFMA), per-expert to reuse He
    for (int e = 0; e < EDIM; e++){
        const unsigned short* Ae  = Xe   + (size_t)e * EROWS * CDIM;
        const unsigned short* B1  = eW1t + (size_t)e * HDIM * CDIM;
        const unsigned short* B2  = eW2t + (size_t)e * CDIM * HDIM;
        const float*          bz1 = eb1  + (size_t)e * HDIM;
        const float*          bz2 = eb2  + (size_t)e * CDIM;
        float*                Oe  = eout + (size_t)e * EROWS * CDIM;
        gemm_bf16_128<<<dim3(EROWS/128, HDIM/128), 256, 0, stream>>>(Ae, B1, bz1, (void*)He, EROWS, HDIM, CDIM, 0);
        gemm_bf16_128<<<dim3(EROWS/128, CDIM/128), 256, 0, stream>>>(He, B2, bz2, (void*)Oe, EROWS, CDIM, HDIM, 1);
    }

    // 6) combine
    combine<<<MTOK, 256, 0, stream>>>(eout, slotr, top2s, out);
}

// Round 5
// 3552.058 us; speedup vs baseline: 2.8138x; 1.1405x over previous
//
#include <hip/hip_runtime.h>
#include <hip/hip_bf16.h>

// Problem constants
#define BDIM 8
#define TDIM 2048
#define CDIM 1024
#define HDIM 4096
#define EDIM 8
#define CAPACITY 320
#define MTOK (BDIM*TDIM)          // 16384
#define MCHUNK 4096               // router M-chunk (per-chunk x split keeps ws ~319 MB)
#define NCHUNKS (MTOK/MCHUNK)     // 4
#define EROWS (BDIM*CAPACITY)     // 2560 rows per expert
#define NROWS (EDIM*EROWS)        // 20480 total slots

typedef __attribute__((ext_vector_type(8))) short bf16x8;
typedef __attribute__((ext_vector_type(8))) _Float16 f16x8;
typedef __attribute__((ext_vector_type(4))) float f32x4;

__device__ __forceinline__ unsigned short f2bf(float f){
    __hip_bfloat16 h = __float2bfloat16(f);
    return *reinterpret_cast<unsigned short*>(&h);
}

// exact 2-term fp16 split: v = hi + lo + O(2^-22 * |v|)
__device__ __forceinline__ void f32_split(float v, unsigned short& h, unsigned short& l){
    _Float16 hh = (_Float16)v;         // RN
    float r = v - (float)hh;           // exact in fp32
    _Float16 ll = (_Float16)r;
    h = __builtin_bit_cast(unsigned short, hh);
    l = __builtin_bit_cast(unsigned short, ll);
}

// async global->LDS, 16B per lane. LDS dest is wave-uniform base + lane*16.
__device__ __forceinline__ void glds16(const unsigned short* g, unsigned short* l){
    __builtin_amdgcn_global_load_lds(
        (const __attribute__((address_space(1))) void*)g,
        (__attribute__((address_space(3))) void*)l,
        16, 0, 0);
}

// XCD-aware bijective block swizzle (requires nwg % 8 == 0, else identity).
__device__ __forceinline__ void xcd_tile(int& bx, int& by){
    int nbx = gridDim.x, nby = gridDim.y;
    int nwg = nbx * nby;
    int orig = blockIdx.y * nbx + blockIdx.x;
    int wg = orig;
    if ((nwg & 7) == 0){
        int cpx = nwg >> 3;
        wg = (orig & 7) * cpx + (orig >> 3);
    }
    bx = wg % nbx;
    by = wg / nbx;
}

// ---------------------------------------------------------------------------
// K0: transpose + fp32->bf16 convert.  in: [z][R][Ccol] f32, out: [z][Ccol][R] bf16
// ---------------------------------------------------------------------------
__global__ __launch_bounds__(256) void transpose_convert(
    const float* __restrict__ in, unsigned short* __restrict__ out, int R, int Ccol)
{
    int z = blockIdx.z;
    in  += (size_t)z * R * Ccol;
    out += (size_t)z * R * Ccol;
    __shared__ float tile[32][33];
    int r0 = blockIdx.y * 32, c0 = blockIdx.x * 32;
    int tid = threadIdx.x;
    int lr = tid >> 5, lc = tid & 31;
    #pragma unroll
    for (int it = 0; it < 4; it++)
        tile[it*8 + lr][lc] = in[(size_t)(r0 + it*8 + lr) * Ccol + c0 + lc];
    __syncthreads();
    #pragma unroll
    for (int it = 0; it < 4; it++){
        float v = tile[lc][it*8 + lr];
        out[(size_t)(c0 + it*8 + lr) * R + r0 + lc] = f2bf(v);
    }
}

// ---------------------------------------------------------------------------
// K0b: transpose + fp32 -> fp16 hi/lo split.  in: [R][Ccol] f32, out hi/lo: [Ccol][R]
// ---------------------------------------------------------------------------
__global__ __launch_bounds__(256) void transpose_split(
    const float* __restrict__ in, unsigned short* __restrict__ hi,
    unsigned short* __restrict__ lo, int R, int Ccol)
{
    __shared__ float tile[32][33];
    int r0 = blockIdx.y * 32, c0 = blockIdx.x * 32;
    int tid = threadIdx.x;
    int lr = tid >> 5, lc = tid & 31;
    #pragma unroll
    for (int it = 0; it < 4; it++)
        tile[it*8 + lr][lc] = in[(size_t)(r0 + it*8 + lr) * Ccol + c0 + lc];
    __syncthreads();
    #pragma unroll
    for (int it = 0; it < 4; it++){
        float v = tile[lc][it*8 + lr];
        unsigned short h, l;
        f32_split(v, h, l);
        size_t o = (size_t)(c0 + it*8 + lr) * R + r0 + lc;
        hi[o] = h; lo[o] = l;
    }
}

// ---------------------------------------------------------------------------
// K0c: elementwise fp32 -> fp16 hi/lo split
// ---------------------------------------------------------------------------
__global__ __launch_bounds__(256) void split_f16(
    const float* __restrict__ in, unsigned short* __restrict__ hi,
    unsigned short* __restrict__ lo, size_t n4)
{
    size_t i = (size_t)blockIdx.x * 256 + threadIdx.x;
    if (i >= n4) return;
    float4 v = ((const float4*)in)[i];
    ushort4 h, l;
    f32_split(v.x, h.x, l.x);
    f32_split(v.y, h.y, l.y);
    f32_split(v.z, h.z, l.z);
    f32_split(v.w, h.w, l.w);
    ((ushort4*)hi)[i] = h;
    ((ushort4*)lo)[i] = l;
}

// ---------------------------------------------------------------------------
// K1/K2: fp32-accurate router GEMM, fp16x3 MFMA, 256x256 tile, BK=32,
// 512 threads = 8 waves (2M x 4N), wave tile 128x64 (8x4 frags of 16x16).
// Same proven 2-phase dbuf sync as r4: prefetch next K-tile -> ds_read cur ->
// MFMA -> single barrier.  Dynamic LDS 128 KiB (8 segs of 16 KiB):
//   seg(arr,buf) arr: 0=A-hi 1=A-lo 2=B-hi 3=B-lo
// XOR-swizzle (both-sides): swz(byte) = byte ^ ((row&6)<<3) within 64B rows.
// mode 0: relu -> f16 hi/lo split outputs.  mode 1: relu -> f32 output.
// grid (M/256, N/256), sharedMem = 131072
// ---------------------------------------------------------------------------
__global__ __launch_bounds__(512, 2) void gemm_f16x3_256(
    const unsigned short* __restrict__ Ahi, const unsigned short* __restrict__ Alo,
    const unsigned short* __restrict__ Bthi, const unsigned short* __restrict__ Btlo,
    const float* __restrict__ bias, void* __restrict__ outA, void* __restrict__ outB,
    int M, int N, int K, int mode)
{
    extern __shared__ unsigned short lds[];   // 8 * 8192 shorts = 128 KiB
    int tid = threadIdx.x;
    int bx, by; xcd_tile(bx, by);
    int m0 = bx * 256, n0 = by * 256;
    int lane = tid & 63, w = tid >> 6;        // 8 waves
    int wm = w >> 2, wn = w & 3;              // 2 x 4 wave grid
    int l15 = lane & 15, quad = lane >> 4;

    f32x4 acc[8][4];
    #pragma unroll
    for (int i = 0; i < 8; i++)
        #pragma unroll
        for (int j = 0; j < 4; j++){ acc[i][j].x=0.f; acc[i][j].y=0.f; acc[i][j].z=0.f; acc[i][j].w=0.f; }

    // staging: each array is 256 rows x 32 shorts (64B rows).  Wave w stages
    // rows [i*128 + w*16, +16) for chunk i in {0,1}; 4 lanes per row, dest
    // byte (lane&3)*16; global source k-offset carries the inverse swizzle.
    const unsigned short *pAh[2], *pAl[2], *pBh[2], *pBl[2];
    int wo[2];
    #pragma unroll
    for (int i = 0; i < 2; i++){
        int r0  = i*128 + w*16;
        int row = r0 + (lane >> 2);
        int ks  = ((lane & 3) * 8) ^ ((row & 6) << 2);   // shorts
        pAh[i] = Ahi  + (size_t)(m0 + row) * K + ks;
        pAl[i] = Alo  + (size_t)(m0 + row) * K + ks;
        pBh[i] = Bthi + (size_t)(n0 + row) * K + ks;
        pBl[i] = Btlo + (size_t)(n0 + row) * K + ks;
        wo[i]  = r0 * 32;
    }

    // fragment read byte-offsets (swizzled)
    int roA[8], roB[4];
    #pragma unroll
    for (int t = 0; t < 8; t++){
        int ra = wm*128 + t*16 + l15;
        roA[t] = (ra*64 + quad*16) ^ ((ra & 6) << 3);
    }
    #pragma unroll
    for (int t = 0; t < 4; t++){
        int rb = wn*64 + t*16 + l15;
        roB[t] = (rb*64 + quad*16) ^ ((rb & 6) << 3);
    }

    unsigned short* seg[8];
    #pragma unroll
    for (int s = 0; s < 8; s++) seg[s] = lds + s * 8192;   // [arr*2+buf]

    // prologue: stage K-tile 0 into buffer 0
    #pragma unroll
    for (int i = 0; i < 2; i++){
        glds16(pAh[i], seg[0] + wo[i]);
        glds16(pAl[i], seg[2] + wo[i]);
        glds16(pBh[i], seg[4] + wo[i]);
        glds16(pBl[i], seg[6] + wo[i]);
    }
    __syncthreads();

    int ntk = K >> 5;
    int cur = 0;
    for (int t = 0; t < ntk; t++){
        if (t + 1 < ntk){
            int ko = (t + 1) * 32;
            #pragma unroll
            for (int i = 0; i < 2; i++){
                glds16(pAh[i] + ko, seg[0 + (cur^1)] + wo[i]);
                glds16(pAl[i] + ko, seg[2 + (cur^1)] + wo[i]);
                glds16(pBh[i] + ko, seg[4 + (cur^1)] + wo[i]);
                glds16(pBl[i] + ko, seg[6 + (cur^1)] + wo[i]);
            }
        }
        f16x8 bh[4], bl[4];
        #pragma unroll
        for (int nt = 0; nt < 4; nt++){
            bh[nt] = *(const f16x8*)((const char*)seg[4 + cur] + roB[nt]);
            bl[nt] = *(const f16x8*)((const char*)seg[6 + cur] + roB[nt]);
        }
        __builtin_amdgcn_s_setprio(1);
        #pragma unroll
        for (int mt = 0; mt < 8; mt++){
            f16x8 amh = *(const f16x8*)((const char*)seg[0 + cur] + roA[mt]);
            f16x8 aml = *(const f16x8*)((const char*)seg[2 + cur] + roA[mt]);
            #pragma unroll
            for (int nt = 0; nt < 4; nt++){
                acc[mt][nt] = __builtin_amdgcn_mfma_f32_16x16x32_f16(amh, bh[nt], acc[mt][nt], 0, 0, 0);
                acc[mt][nt] = __builtin_amdgcn_mfma_f32_16x16x32_f16(amh, bl[nt], acc[mt][nt], 0, 0, 0);
                acc[mt][nt] = __builtin_amdgcn_mfma_f32_16x16x32_f16(aml, bh[nt], acc[mt][nt], 0, 0, 0);
            }
        }
        __builtin_amdgcn_s_setprio(0);
        __syncthreads();
        cur ^= 1;
    }

    #pragma unroll
    for (int mt = 0; mt < 8; mt++)
        #pragma unroll
        for (int nt = 0; nt < 4; nt++){
            int mb = m0 + wm*128 + mt*16 + quad*4;
            int n  = n0 + wn*64 + nt*16 + l15;
            float bz = bias[n];
            #pragma unroll
            for (int r = 0; r < 4; r++){
                float v = fmaxf(acc[mt][nt][r] + bz, 0.f);
                int m = mb + r;
                if (mode == 0){
                    unsigned short h, l;
                    f32_split(v, h, l);
                    ((unsigned short*)outA)[(size_t)m * N + n] = h;
                    ((unsigned short*)outB)[(size_t)m * N + n] = l;
                } else {
                    ((float*)outA)[(size_t)m * N + n] = v;
                }
            }
        }
}

// ---------------------------------------------------------------------------
// K6/K7: bf16 MFMA GEMM, 128x128 tile, BK=32, r4-proven dbuf/swizzle structure,
// expert-batched via blockIdx.z with per-z strides (elements).
// mode 0: relu -> bf16 out.  mode 1: plain -> f32 out.
// grid (M/128, N/128, nz)
// ---------------------------------------------------------------------------
__global__ __launch_bounds__(256) void gemm_bf16_128(
    const unsigned short* __restrict__ A, const unsigned short* __restrict__ Bt,
    const float* __restrict__ bias, void* __restrict__ outv,
    int M, int N, int K, int mode,
    size_t zsA, size_t zsB, size_t zsb, size_t zsO)
{
    __shared__ unsigned short As[2][128*32];
    __shared__ unsigned short Bs[2][128*32];
    int z = blockIdx.z;
    A    += (size_t)z * zsA;
    Bt   += (size_t)z * zsB;
    bias += (size_t)z * zsb;
    int tid = threadIdx.x;
    int bx, by; xcd_tile(bx, by);
    int m0 = bx * 128, n0 = by * 128;
    int lane = tid & 63, w = tid >> 6;
    int wm = w & 1, wn = w >> 1;
    int l15 = lane & 15, quad = lane >> 4;

    f32x4 acc[4][4];
    #pragma unroll
    for (int i = 0; i < 4; i++)
        #pragma unroll
        for (int j = 0; j < 4; j++){ acc[i][j].x=0.f; acc[i][j].y=0.f; acc[i][j].z=0.f; acc[i][j].w=0.f; }

    const unsigned short *pA[2], *pB[2];
    int wo[2];
    #pragma unroll
    for (int i = 0; i < 2; i++){
        int r0  = w*32 + i*16;
        int row = r0 + (lane >> 2);
        int ks  = ((lane & 3) * 8) ^ ((row & 6) << 2);
        pA[i] = A  + (size_t)(m0 + row) * K + ks;
        pB[i] = Bt + (size_t)(n0 + row) * K + ks;
        wo[i] = r0 * 32;
    }

    int roA[4], roB[4];
    #pragma unroll
    for (int t = 0; t < 4; t++){
        int ra = wm*64 + t*16 + l15;
        roA[t] = (ra*64 + quad*16) ^ ((ra & 6) << 3);
        int rb = wn*64 + t*16 + l15;
        roB[t] = (rb*64 + quad*16) ^ ((rb & 6) << 3);
    }

    #pragma unroll
    for (int i = 0; i < 2; i++){
        glds16(pA[i], &As[0][wo[i]]);
        glds16(pB[i], &Bs[0][wo[i]]);
    }
    __syncthreads();

    int ntk = K >> 5;
    int cur = 0;
    for (int t = 0; t < ntk; t++){
        if (t + 1 < ntk){
            int ko = (t + 1) * 32;
            #pragma unroll
            for (int i = 0; i < 2; i++){
                glds16(pA[i] + ko, &As[cur^1][wo[i]]);
                glds16(pB[i] + ko, &Bs[cur^1][wo[i]]);
            }
        }
        bf16x8 af[4], bf[4];
        #pragma unroll
        for (int t4 = 0; t4 < 4; t4++){
            af[t4] = *(const bf16x8*)((const char*)As[cur] + roA[t4]);
            bf[t4] = *(const bf16x8*)((const char*)Bs[cur] + roB[t4]);
        }
        __builtin_amdgcn_s_setprio(1);
        #pragma unroll
        for (int mt = 0; mt < 4; mt++)
            #pragma unroll
            for (int nt2 = 0; nt2 < 4; nt2++)
                acc[mt][nt2] = __builtin_amdgcn_mfma_f32_16x16x32_bf16(af[mt], bf[nt2], acc[mt][nt2], 0, 0, 0);
        __builtin_amdgcn_s_setprio(0);
        __syncthreads();
        cur ^= 1;
    }

    #pragma unroll
    for (int mt = 0; mt < 4; mt++)
        #pragma unroll
        for (int nt2 = 0; nt2 < 4; nt2++){
            int mb = m0 + wm*64 + mt*16 + quad*4;
            int n  = n0 + wn*64 + nt2*16 + l15;
            float bz = bias[n];
            #pragma unroll
            for (int r = 0; r < 4; r++){
                float v = acc[mt][nt2][r] + bz;
                int m = mb + r;
                if (mode == 0){
                    v = fmaxf(v, 0.f);
                    ((unsigned short*)outv)[(size_t)z * zsO + (size_t)m * N + n] = f2bf(v);
                } else {
                    ((float*)outv)[(size_t)z * zsO + (size_t)m * N + n] = v;
                }
            }
        }
}

// ---------------------------------------------------------------------------
// K3: router head. logits = h2 @ rW3 + rb3; softmax (double); top-2 w/ tie->low idx
// ---------------------------------------------------------------------------
__global__ __launch_bounds__(256) void router_head(
    const float* __restrict__ h2, const float* __restrict__ W3,
    const float* __restrict__ b3, int tokBase,
    int* __restrict__ top2e, float* __restrict__ top2s)
{
    int tid = threadIdx.x;
    int tloc = blockIdx.x * 32 + (tid >> 3);
    int e = tid & 7;
    const float* hrow = h2 + (size_t)tloc * HDIM;
    float acc = 0.f;
    for (int k = 0; k < HDIM; k += 4){
        float4 h = *(const float4*)(hrow + k);
        acc = fmaf(h.x, W3[(k+0)*8 + e], acc);
        acc = fmaf(h.y, W3[(k+1)*8 + e], acc);
        acc = fmaf(h.z, W3[(k+2)*8 + e], acc);
        acc = fmaf(h.w, W3[(k+3)*8 + e], acc);
    }
    float logit = acc + b3[e];
    __shared__ float lg[32][8];
    lg[tid >> 3][e] = logit;
    __syncthreads();
    if (tid < 32){
        double l[8];
        double mx = -1e300;
        for (int i = 0; i < 8; i++){ l[i] = (double)lg[tid][i]; if (l[i] > mx) mx = l[i]; }
        double ex[8]; double s = 0.0;
        for (int i = 0; i < 8; i++){ ex[i] = exp(l[i] - mx); s += ex[i]; }
        double b1v = -1.0, b2v = -1.0; int e1 = 0, e2 = 0;
        for (int i = 0; i < 8; i++){
            double v = ex[i];
            if (v > b1v){ b2v = b1v; e2 = e1; b1v = v; e1 = i; }
            else if (v > b2v){ b2v = v; e2 = i; }
        }
        int gt = tokBase + blockIdx.x * 32 + tid;
        top2e[gt*2 + 0] = e1;
        top2e[gt*2 + 1] = e2;
        top2s[gt*2 + 0] = (float)(b1v / s);
        top2s[gt*2 + 1] = (float)(b2v / s);
    }
}

// ---------------------------------------------------------------------------
// K4: dispatch scan. One block per batch row b. Exact (t, slot) cumsum order.
// ---------------------------------------------------------------------------
__global__ __launch_bounds__(256) void scan_dispatch(
    const int* __restrict__ top2e, int* __restrict__ slot_row, int* __restrict__ row2tok)
{
    int b = blockIdx.x;
    int tid = threadIdx.x;
    __shared__ int cnt[256][8];
    int base = b * (TDIM * 2);
    int i0 = tid * 16;
    int c[8];
    #pragma unroll
    for (int e = 0; e < 8; e++) c[e] = 0;
    for (int j = 0; j < 16; j++){
        int e = top2e[base + i0 + j];
        c[e]++;
    }
    #pragma unroll
    for (int e = 0; e < 8; e++) cnt[tid][e] = c[e];
    __syncthreads();
    if (tid < 8){
        int run = 0;
        for (int t = 0; t < 256; t++){ int v = cnt[t][tid]; cnt[t][tid] = run; run += v; }
    }
    __syncthreads();
    int offs[8];
    #pragma unroll
    for (int e = 0; e < 8; e++) offs[e] = cnt[tid][e];
    for (int j = 0; j < 16; j++){
        int i = i0 + j;
        int e = top2e[base + i];
        int pos = offs[e]++;
        int r = (pos < CAPACITY) ? ((e * BDIM + b) * CAPACITY + pos) : -1;
        slot_row[base + i] = r;
        if (r >= 0) row2tok[r] = b * TDIM + (i >> 1);
    }
}

// ---------------------------------------------------------------------------
// K5: gather tokens into expert slot buffer (bf16). One block per slot row.
// ---------------------------------------------------------------------------
__global__ __launch_bounds__(256) void gather_rows(
    const float* __restrict__ x, const int* __restrict__ row2tok,
    unsigned short* __restrict__ Xe)
{
    int r = blockIdx.x;
    int tid = threadIdx.x;
    int tok = row2tok[r];
    unsigned short* dst = Xe + (size_t)r * CDIM + tid * 4;
    if (tok >= 0){
        float4 v = *(const float4*)(x + (size_t)tok * CDIM + tid * 4);
        ushort4 o;
        o.x = f2bf(v.x); o.y = f2bf(v.y); o.z = f2bf(v.z); o.w = f2bf(v.w);
        *(ushort4*)dst = o;
    } else {
        ushort4 o; o.x = o.y = o.z = o.w = 0;
        *(ushort4*)dst = o;
    }
}

// ---------------------------------------------------------------------------
// K8: combine. out[b,t,:] = s1*eout[r1,:] + s2*eout[r2,:] (dropped -> 0)
// ---------------------------------------------------------------------------
__global__ __launch_bounds__(256) void combine(
    const float* __restrict__ eout, const int* __restrict__ slot_row,
    const float* __restrict__ top2s, float* __restrict__ out)
{
    int gt = blockIdx.x;
    int b = gt >> 11, t = gt & (TDIM - 1);
    int i = b * (TDIM * 2) + t * 2;
    int r1 = slot_row[i], r2 = slot_row[i + 1];
    float s1 = top2s[gt*2 + 0], s2 = top2s[gt*2 + 1];
    int c = threadIdx.x * 4;
    float4 acc; acc.x = acc.y = acc.z = acc.w = 0.f;
    if (r1 >= 0){
        float4 v = *(const float4*)(eout + (size_t)r1 * CDIM + c);
        acc.x = fmaf(s1, v.x, acc.x); acc.y = fmaf(s1, v.y, acc.y);
        acc.z = fmaf(s1, v.z, acc.z); acc.w = fmaf(s1, v.w, acc.w);
    }
    if (r2 >= 0){
        float4 v = *(const float4*)(eout + (size_t)r2 * CDIM + c);
        acc.x = fmaf(s2, v.x, acc.x); acc.y = fmaf(s2, v.y, acc.y);
        acc.z = fmaf(s2, v.z, acc.z); acc.w = fmaf(s2, v.w, acc.w);
    }
    *(float4*)(out + (size_t)gt * CDIM + c) = acc;
}

// ---------------------------------------------------------------------------
extern "C" void kernel_launch(void* const* d_in, const int* in_sizes, int n_in,
                              void* d_out, int out_size, void* d_ws, size_t ws_size,
                              hipStream_t stream)
{
    const float* x   = (const float*)d_in[0];
    const float* rW1 = (const float*)d_in[1];
    const float* rb1 = (const float*)d_in[2];
    const float* rW2 = (const float*)d_in[3];
    const float* rb2 = (const float*)d_in[4];
    const float* rW3 = (const float*)d_in[5];
    const float* rb3 = (const float*)d_in[6];
    const float* eW1 = (const float*)d_in[7];
    const float* eb1 = (const float*)d_in[8];
    const float* eW2 = (const float*)d_in[9];
    const float* eb2 = (const float*)d_in[10];
    float* out = (float*)d_out;

    // allow 128 KiB dynamic LDS for the 256x256 router GEMM (once)
    static bool attr_done = false;
    if (!attr_done){
        hipFuncSetAttribute((const void*)gemm_f16x3_256,
                            hipFuncAttributeMaxDynamicSharedMemorySize, 131072);
        attr_done = true;
    }

    // workspace carve-up (all 256B aligned).
    // Persistent ~84.4 MB + UNION region:
    //   phase A (router, MCHUNK=4096, per-chunk x split): ~234.9 MB -> total ~319 MB
    //   phase B (experts, He for 2 experts): ~218 MB -> total ~302 MB
    // (r0-proven ceiling ~349 MB)
    char* p = (char*)d_ws;
    auto alloc = [&](size_t bytes) -> void* {
        void* q = (void*)p;
        p += (bytes + 255) & ~(size_t)255;
        return q;
    };
    int*            top2e = (int*)alloc((size_t)MTOK * 2 * 4);
    float*          top2s = (float*)alloc((size_t)MTOK * 2 * 4);
    int*            slotr = (int*)alloc((size_t)BDIM * TDIM * 2 * 4);
    int*            r2tok = (int*)alloc((size_t)NROWS * 4);
    float*          eout  = (float*)alloc((size_t)NROWS * CDIM * 4);           // 84 MB
    char* ubase = p;

    // ---- phase A layout (router) ----
    unsigned short* Xchi  = (unsigned short*)alloc((size_t)MCHUNK * CDIM * 2); // 8.4 MB
    unsigned short* Xclo  = (unsigned short*)alloc((size_t)MCHUNK * CDIM * 2); // 8.4 MB
    unsigned short* W1thi = (unsigned short*)alloc((size_t)HDIM * CDIM * 2);   // 8.4 MB
    unsigned short* W1tlo = (unsigned short*)alloc((size_t)HDIM * CDIM * 2);   // 8.4 MB
    unsigned short* W2thi = (unsigned short*)alloc((size_t)HDIM * HDIM * 2);   // 33.5 MB
    unsigned short* W2tlo = (unsigned short*)alloc((size_t)HDIM * HDIM * 2);   // 33.5 MB
    unsigned short* H1hi  = (unsigned short*)alloc((size_t)MCHUNK * HDIM * 2); // 33.5 MB
    unsigned short* H1lo  = (unsigned short*)alloc((size_t)MCHUNK * HDIM * 2); // 33.5 MB
    float*          h2c   = (float*)alloc((size_t)MCHUNK * HDIM * 4);          // 67 MB

    // ---- phase B layout (experts) — aliases phase A ----
    p = ubase;
    unsigned short* Xe    = (unsigned short*)alloc((size_t)NROWS * CDIM * 2);      // 42 MB
    unsigned short* He    = (unsigned short*)alloc((size_t)2 * EROWS * HDIM * 2);  // 42 MB (2 experts)
    unsigned short* eW1t  = (unsigned short*)alloc((size_t)EDIM * HDIM * CDIM * 2); // 67 MB
    unsigned short* eW2t  = (unsigned short*)alloc((size_t)EDIM * CDIM * HDIM * 2); // 67 MB

    // 1) router weights -> fp16 hi/lo splits (transposed to [N][K])
    transpose_split<<<dim3(HDIM/32, CDIM/32), 256, 0, stream>>>(rW1, W1thi, W1tlo, CDIM, HDIM);
    transpose_split<<<dim3(HDIM/32, HDIM/32), 256, 0, stream>>>(rW2, W2thi, W2tlo, HDIM, HDIM);

    // 2) router, chunked over tokens (fp16x3 MFMA = fp32-accurate)
    for (int mc = 0; mc < NCHUNKS; mc++){
        split_f16<<<(MCHUNK * CDIM / 4 + 255) / 256, 256, 0, stream>>>(
            x + (size_t)mc * MCHUNK * CDIM, Xchi, Xclo, (size_t)MCHUNK * CDIM / 4);
        gemm_f16x3_256<<<dim3(MCHUNK/256, HDIM/256), 512, 131072, stream>>>(
            Xchi, Xclo, W1thi, W1tlo, rb1, (void*)H1hi, (void*)H1lo, MCHUNK, HDIM, CDIM, 0);
        gemm_f16x3_256<<<dim3(MCHUNK/256, HDIM/256), 512, 131072, stream>>>(
            H1hi, H1lo, W2thi, W2tlo, rb2, (void*)h2c, nullptr, MCHUNK, HDIM, HDIM, 1);
        router_head<<<MCHUNK/32, 256, 0, stream>>>(h2c, rW3, rb3, mc * MCHUNK, top2e, top2s);
    }

    // 3) dispatch (phase A buffers dead from here on)
    hipMemsetAsync(r2tok, 0xFF, (size_t)NROWS * 4, stream);
    scan_dispatch<<<BDIM, 256, 0, stream>>>(top2e, slotr, r2tok);
    gather_rows<<<NROWS, 256, 0, stream>>>(x, r2tok, Xe);

    // 4) expert weights -> bf16, transposed to [N][K]
    transpose_convert<<<dim3(HDIM/32, CDIM/32, EDIM), 256, 0, stream>>>(eW1, eW1t, CDIM, HDIM);
    transpose_convert<<<dim3(CDIM/32, HDIM/32, EDIM), 256, 0, stream>>>(eW2, eW2t, HDIM, CDIM);

    // 5) expert FFNs (bf16 MFMA), 2 experts per launch via grid.z
    for (int g = 0; g < EDIM/2; g++){
        int e0 = g * 2;
        gemm_bf16_128<<<dim3(EROWS/128, HDIM/128, 2), 256, 0, stream>>>(
            Xe + (size_t)e0 * EROWS * CDIM, eW1t + (size_t)e0 * HDIM * CDIM,
            eb1 + (size_t)e0 * HDIM, (void*)He,
            EROWS, HDIM, CDIM, 0,
            (size_t)EROWS * CDIM, (size_t)HDIM * CDIM, (size_t)HDIM, (size_t)EROWS * HDIM);
        gemm_bf16_128<<<dim3(EROWS/128, CDIM/128, 2), 256, 0, stream>>>(
            He, eW2t + (size_t)e0 * CDIM * HDIM,
            eb2 + (size_t)e0 * CDIM, (void*)(eout + (size_t)e0 * EROWS * CDIM),
            EROWS, CDIM, HDIM, 1,
            (size_t)EROWS * HDIM, (size_t)CDIM * HDIM, (size_t)CDIM, (size_t)EROWS * CDIM);
    }

    // 6) combine
    combine<<<MTOK, 256, 0, stream>>>(eout, slotr, top2s, out);
}

// Round 6
// 3531.208 us; speedup vs baseline: 2.8304x; 1.0059x over previous
//
#include <hip/hip_runtime.h>
#include <hip/hip_bf16.h>

// Problem constants
#define BDIM 8
#define TDIM 2048
#define CDIM 1024
#define HDIM 4096
#define EDIM 8
#define CAPACITY 320
#define MTOK (BDIM*TDIM)          // 16384
#define MCHUNK 4096               // router M-chunk (per-chunk x split keeps ws ~319 MB)
#define NCHUNKS (MTOK/MCHUNK)     // 4
#define EROWS (BDIM*CAPACITY)     // 2560 rows per expert
#define NROWS (EDIM*EROWS)        // 20480 total slots

typedef __attribute__((ext_vector_type(8))) short bf16x8;
typedef __attribute__((ext_vector_type(8))) _Float16 f16x8;
typedef __attribute__((ext_vector_type(4))) float f32x4;

__device__ __forceinline__ unsigned short f2bf(float f){
    __hip_bfloat16 h = __float2bfloat16(f);
    return *reinterpret_cast<unsigned short*>(&h);
}

// exact 2-term fp16 split: v = hi + lo + O(2^-22 * |v|)
__device__ __forceinline__ void f32_split(float v, unsigned short& h, unsigned short& l){
    _Float16 hh = (_Float16)v;         // RN
    float r = v - (float)hh;           // exact in fp32
    _Float16 ll = (_Float16)r;
    h = __builtin_bit_cast(unsigned short, hh);
    l = __builtin_bit_cast(unsigned short, ll);
}

// async global->LDS, 16B per lane. LDS dest is wave-uniform base + lane*16.
__device__ __forceinline__ void glds16(const unsigned short* g, unsigned short* l){
    __builtin_amdgcn_global_load_lds(
        (const __attribute__((address_space(1))) void*)g,
        (__attribute__((address_space(3))) void*)l,
        16, 0, 0);
}

// XCD-aware bijective block swizzle (requires nwg % 8 == 0, else identity).
__device__ __forceinline__ void xcd_tile(int& bx, int& by){
    int nbx = gridDim.x, nby = gridDim.y;
    int nwg = nbx * nby;
    int orig = blockIdx.y * nbx + blockIdx.x;
    int wg = orig;
    if ((nwg & 7) == 0){
        int cpx = nwg >> 3;
        wg = (orig & 7) * cpx + (orig >> 3);
    }
    bx = wg % nbx;
    by = wg / nbx;
}

// ---------------------------------------------------------------------------
// K0: transpose + fp32->bf16 convert.  in: [z][R][Ccol] f32, out: [z][Ccol][R] bf16
// ---------------------------------------------------------------------------
__global__ __launch_bounds__(256) void transpose_convert(
    const float* __restrict__ in, unsigned short* __restrict__ out, int R, int Ccol)
{
    int z = blockIdx.z;
    in  += (size_t)z * R * Ccol;
    out += (size_t)z * R * Ccol;
    __shared__ float tile[32][33];
    int r0 = blockIdx.y * 32, c0 = blockIdx.x * 32;
    int tid = threadIdx.x;
    int lr = tid >> 5, lc = tid & 31;
    #pragma unroll
    for (int it = 0; it < 4; it++)
        tile[it*8 + lr][lc] = in[(size_t)(r0 + it*8 + lr) * Ccol + c0 + lc];
    __syncthreads();
    #pragma unroll
    for (int it = 0; it < 4; it++){
        float v = tile[lc][it*8 + lr];
        out[(size_t)(c0 + it*8 + lr) * R + r0 + lc] = f2bf(v);
    }
}

// ---------------------------------------------------------------------------
// K0b: transpose + fp32 -> fp16 hi/lo split.  in: [R][Ccol] f32, out hi/lo: [Ccol][R]
// ---------------------------------------------------------------------------
__global__ __launch_bounds__(256) void transpose_split(
    const float* __restrict__ in, unsigned short* __restrict__ hi,
    unsigned short* __restrict__ lo, int R, int Ccol)
{
    __shared__ float tile[32][33];
    int r0 = blockIdx.y * 32, c0 = blockIdx.x * 32;
    int tid = threadIdx.x;
    int lr = tid >> 5, lc = tid & 31;
    #pragma unroll
    for (int it = 0; it < 4; it++)
        tile[it*8 + lr][lc] = in[(size_t)(r0 + it*8 + lr) * Ccol + c0 + lc];
    __syncthreads();
    #pragma unroll
    for (int it = 0; it < 4; it++){
        float v = tile[lc][it*8 + lr];
        unsigned short h, l;
        f32_split(v, h, l);
        size_t o = (size_t)(c0 + it*8 + lr) * R + r0 + lc;
        hi[o] = h; lo[o] = l;
    }
}

// ---------------------------------------------------------------------------
// K0c: elementwise fp32 -> fp16 hi/lo split
// ---------------------------------------------------------------------------
__global__ __launch_bounds__(256) void split_f16(
    const float* __restrict__ in, unsigned short* __restrict__ hi,
    unsigned short* __restrict__ lo, size_t n4)
{
    size_t i = (size_t)blockIdx.x * 256 + threadIdx.x;
    if (i >= n4) return;
    float4 v = ((const float4*)in)[i];
    ushort4 h, l;
    f32_split(v.x, h.x, l.x);
    f32_split(v.y, h.y, l.y);
    f32_split(v.z, h.z, l.z);
    f32_split(v.w, h.w, l.w);
    ((ushort4*)hi)[i] = h;
    ((ushort4*)lo)[i] = l;
}

// ---------------------------------------------------------------------------
// K1/K2: fp32-accurate router GEMM, fp16x3 MFMA, 128x128 tile, BK=32,
// r4-PROVEN 2-phase dbuf: prefetch next K-tile -> ds_read cur -> MFMA ->
// single barrier (implicit vmcnt(0)+lgkmcnt(0) drain = correctness sync).
// 64 KiB LDS -> 2 blocks/CU; inter-block overlap hides the barrier drain.
// XOR-swizzle (both-sides): swz(byte) = byte ^ ((row&6)<<3) in 64B rows.
// mode 0: relu -> f16 hi/lo split outputs.  mode 1: relu -> f32 output.
// grid (M/128, N/128)
// ---------------------------------------------------------------------------
__global__ __launch_bounds__(256) void gemm_f16x3_128(
    const unsigned short* __restrict__ Ahi, const unsigned short* __restrict__ Alo,
    const unsigned short* __restrict__ Bthi, const unsigned short* __restrict__ Btlo,
    const float* __restrict__ bias, void* __restrict__ outA, void* __restrict__ outB,
    int M, int N, int K, int mode)
{
    __shared__ unsigned short AsH[2][128*32];  // [buf][row][k] linear, 64B rows
    __shared__ unsigned short AsL[2][128*32];
    __shared__ unsigned short BsH[2][128*32];
    __shared__ unsigned short BsL[2][128*32];
    int tid = threadIdx.x;
    int bx, by; xcd_tile(bx, by);
    int m0 = bx * 128, n0 = by * 128;
    int lane = tid & 63, w = tid >> 6;
    int wm = w & 1, wn = w >> 1;
    int l15 = lane & 15, quad = lane >> 4;

    f32x4 acc[4][4];
    #pragma unroll
    for (int i = 0; i < 4; i++)
        #pragma unroll
        for (int j = 0; j < 4; j++){ acc[i][j].x=0.f; acc[i][j].y=0.f; acc[i][j].z=0.f; acc[i][j].w=0.f; }

    // staging: wave w covers rows [w*32, w*32+32), 2 chunks x 16 rows.
    const unsigned short *pAh[2], *pAl[2], *pBh[2], *pBl[2];
    int wo[2];
    #pragma unroll
    for (int i = 0; i < 2; i++){
        int r0  = w*32 + i*16;
        int row = r0 + (lane >> 2);
        int ks  = ((lane & 3) * 8) ^ ((row & 6) << 2);   // shorts
        pAh[i] = Ahi  + (size_t)(m0 + row) * K + ks;
        pAl[i] = Alo  + (size_t)(m0 + row) * K + ks;
        pBh[i] = Bthi + (size_t)(n0 + row) * K + ks;
        pBl[i] = Btlo + (size_t)(n0 + row) * K + ks;
        wo[i]  = r0 * 32;
    }

    // fragment read byte-offsets (swizzled)
    int roA[4], roB[4];
    #pragma unroll
    for (int t = 0; t < 4; t++){
        int ra = wm*64 + t*16 + l15;
        roA[t] = (ra*64 + quad*16) ^ ((ra & 6) << 3);
        int rb = wn*64 + t*16 + l15;
        roB[t] = (rb*64 + quad*16) ^ ((rb & 6) << 3);
    }

    // prologue: stage K-tile 0 into buffer 0
    #pragma unroll
    for (int i = 0; i < 2; i++){
        glds16(pAh[i], &AsH[0][wo[i]]);
        glds16(pAl[i], &AsL[0][wo[i]]);
        glds16(pBh[i], &BsH[0][wo[i]]);
        glds16(pBl[i], &BsL[0][wo[i]]);
    }
    __syncthreads();

    int ntk = K >> 5;
    int cur = 0;
    for (int t = 0; t < ntk; t++){
        if (t + 1 < ntk){
            int ko = (t + 1) * 32;
            #pragma unroll
            for (int i = 0; i < 2; i++){
                glds16(pAh[i] + ko, &AsH[cur^1][wo[i]]);
                glds16(pAl[i] + ko, &AsL[cur^1][wo[i]]);
                glds16(pBh[i] + ko, &BsH[cur^1][wo[i]]);
                glds16(pBl[i] + ko, &BsL[cur^1][wo[i]]);
            }
        }
        f16x8 ah[4], al[4], bh[4], bl[4];
        #pragma unroll
        for (int t4 = 0; t4 < 4; t4++){
            ah[t4] = *(const f16x8*)((const char*)AsH[cur] + roA[t4]);
            al[t4] = *(const f16x8*)((const char*)AsL[cur] + roA[t4]);
            bh[t4] = *(const f16x8*)((const char*)BsH[cur] + roB[t4]);
            bl[t4] = *(const f16x8*)((const char*)BsL[cur] + roB[t4]);
        }
        __builtin_amdgcn_s_setprio(1);
        #pragma unroll
        for (int mt = 0; mt < 4; mt++)
            #pragma unroll
            for (int nt2 = 0; nt2 < 4; nt2++){
                acc[mt][nt2] = __builtin_amdgcn_mfma_f32_16x16x32_f16(ah[mt], bh[nt2], acc[mt][nt2], 0, 0, 0);
                acc[mt][nt2] = __builtin_amdgcn_mfma_f32_16x16x32_f16(ah[mt], bl[nt2], acc[mt][nt2], 0, 0, 0);
                acc[mt][nt2] = __builtin_amdgcn_mfma_f32_16x16x32_f16(al[mt], bh[nt2], acc[mt][nt2], 0, 0, 0);
            }
        __builtin_amdgcn_s_setprio(0);
        __syncthreads();
        cur ^= 1;
    }

    #pragma unroll
    for (int mt = 0; mt < 4; mt++)
        #pragma unroll
        for (int nt2 = 0; nt2 < 4; nt2++){
            int mb = m0 + wm*64 + mt*16 + quad*4;
            int n  = n0 + wn*64 + nt2*16 + l15;
            float bz = bias[n];
            #pragma unroll
            for (int r = 0; r < 4; r++){
                float v = fmaxf(acc[mt][nt2][r] + bz, 0.f);
                int m = mb + r;
                if (mode == 0){
                    unsigned short h, l;
                    f32_split(v, h, l);
                    ((unsigned short*)outA)[(size_t)m * N + n] = h;
                    ((unsigned short*)outB)[(size_t)m * N + n] = l;
                } else {
                    ((float*)outA)[(size_t)m * N + n] = v;
                }
            }
        }
}

// ---------------------------------------------------------------------------
// K6/K7: bf16 MFMA GEMM, 128x128 tile, BK=32, r4-proven dbuf/swizzle structure,
// expert-batched via blockIdx.z with per-z strides (elements).
// mode 0: relu -> bf16 out.  mode 1: plain -> f32 out.
// grid (M/128, N/128, nz)
// ---------------------------------------------------------------------------
__global__ __launch_bounds__(256) void gemm_bf16_128(
    const unsigned short* __restrict__ A, const unsigned short* __restrict__ Bt,
    const float* __restrict__ bias, void* __restrict__ outv,
    int M, int N, int K, int mode,
    size_t zsA, size_t zsB, size_t zsb, size_t zsO)
{
    __shared__ unsigned short As[2][128*32];
    __shared__ unsigned short Bs[2][128*32];
    int z = blockIdx.z;
    A    += (size_t)z * zsA;
    Bt   += (size_t)z * zsB;
    bias += (size_t)z * zsb;
    int tid = threadIdx.x;
    int bx, by; xcd_tile(bx, by);
    int m0 = bx * 128, n0 = by * 128;
    int lane = tid & 63, w = tid >> 6;
    int wm = w & 1, wn = w >> 1;
    int l15 = lane & 15, quad = lane >> 4;

    f32x4 acc[4][4];
    #pragma unroll
    for (int i = 0; i < 4; i++)
        #pragma unroll
        for (int j = 0; j < 4; j++){ acc[i][j].x=0.f; acc[i][j].y=0.f; acc[i][j].z=0.f; acc[i][j].w=0.f; }

    const unsigned short *pA[2], *pB[2];
    int wo[2];
    #pragma unroll
    for (int i = 0; i < 2; i++){
        int r0  = w*32 + i*16;
        int row = r0 + (lane >> 2);
        int ks  = ((lane & 3) * 8) ^ ((row & 6) << 2);
        pA[i] = A  + (size_t)(m0 + row) * K + ks;
        pB[i] = Bt + (size_t)(n0 + row) * K + ks;
        wo[i] = r0 * 32;
    }

    int roA[4], roB[4];
    #pragma unroll
    for (int t = 0; t < 4; t++){
        int ra = wm*64 + t*16 + l15;
        roA[t] = (ra*64 + quad*16) ^ ((ra & 6) << 3);
        int rb = wn*64 + t*16 + l15;
        roB[t] = (rb*64 + quad*16) ^ ((rb & 6) << 3);
    }

    #pragma unroll
    for (int i = 0; i < 2; i++){
        glds16(pA[i], &As[0][wo[i]]);
        glds16(pB[i], &Bs[0][wo[i]]);
    }
    __syncthreads();

    int ntk = K >> 5;
    int cur = 0;
    for (int t = 0; t < ntk; t++){
        if (t + 1 < ntk){
            int ko = (t + 1) * 32;
            #pragma unroll
            for (int i = 0; i < 2; i++){
                glds16(pA[i] + ko, &As[cur^1][wo[i]]);
                glds16(pB[i] + ko, &Bs[cur^1][wo[i]]);
            }
        }
        bf16x8 af[4], bf[4];
        #pragma unroll
        for (int t4 = 0; t4 < 4; t4++){
            af[t4] = *(const bf16x8*)((const char*)As[cur] + roA[t4]);
            bf[t4] = *(const bf16x8*)((const char*)Bs[cur] + roB[t4]);
        }
        __builtin_amdgcn_s_setprio(1);
        #pragma unroll
        for (int mt = 0; mt < 4; mt++)
            #pragma unroll
            for (int nt2 = 0; nt2 < 4; nt2++)
                acc[mt][nt2] = __builtin_amdgcn_mfma_f32_16x16x32_bf16(af[mt], bf[nt2], acc[mt][nt2], 0, 0, 0);
        __builtin_amdgcn_s_setprio(0);
        __syncthreads();
        cur ^= 1;
    }

    #pragma unroll
    for (int mt = 0; mt < 4; mt++)
        #pragma unroll
        for (int nt2 = 0; nt2 < 4; nt2++){
            int mb = m0 + wm*64 + mt*16 + quad*4;
            int n  = n0 + wn*64 + nt2*16 + l15;
            float bz = bias[n];
            #pragma unroll
            for (int r = 0; r < 4; r++){
                float v = acc[mt][nt2][r] + bz;
                int m = mb + r;
                if (mode == 0){
                    v = fmaxf(v, 0.f);
                    ((unsigned short*)outv)[(size_t)z * zsO + (size_t)m * N + n] = f2bf(v);
                } else {
                    ((float*)outv)[(size_t)z * zsO + (size_t)m * N + n] = v;
                }
            }
        }
}

// ---------------------------------------------------------------------------
// K3: router head. logits = h2 @ rW3 + rb3; softmax (double); top-2 w/ tie->low idx
// ---------------------------------------------------------------------------
__global__ __launch_bounds__(256) void router_head(
    const float* __restrict__ h2, const float* __restrict__ W3,
    const float* __restrict__ b3, int tokBase,
    int* __restrict__ top2e, float* __restrict__ top2s)
{
    int tid = threadIdx.x;
    int tloc = blockIdx.x * 32 + (tid >> 3);
    int e = tid & 7;
    const float* hrow = h2 + (size_t)tloc * HDIM;
    float acc = 0.f;
    for (int k = 0; k < HDIM; k += 4){
        float4 h = *(const float4*)(hrow + k);
        acc = fmaf(h.x, W3[(k+0)*8 + e], acc);
        acc = fmaf(h.y, W3[(k+1)*8 + e], acc);
        acc = fmaf(h.z, W3[(k+2)*8 + e], acc);
        acc = fmaf(h.w, W3[(k+3)*8 + e], acc);
    }
    float logit = acc + b3[e];
    __shared__ float lg[32][8];
    lg[tid >> 3][e] = logit;
    __syncthreads();
    if (tid < 32){
        double l[8];
        double mx = -1e300;
        for (int i = 0; i < 8; i++){ l[i] = (double)lg[tid][i]; if (l[i] > mx) mx = l[i]; }
        double ex[8]; double s = 0.0;
        for (int i = 0; i < 8; i++){ ex[i] = exp(l[i] - mx); s += ex[i]; }
        double b1v = -1.0, b2v = -1.0; int e1 = 0, e2 = 0;
        for (int i = 0; i < 8; i++){
            double v = ex[i];
            if (v > b1v){ b2v = b1v; e2 = e1; b1v = v; e1 = i; }
            else if (v > b2v){ b2v = v; e2 = i; }
        }
        int gt = tokBase + blockIdx.x * 32 + tid;
        top2e[gt*2 + 0] = e1;
        top2e[gt*2 + 1] = e2;
        top2s[gt*2 + 0] = (float)(b1v / s);
        top2s[gt*2 + 1] = (float)(b2v / s);
    }
}

// ---------------------------------------------------------------------------
// K4: dispatch scan. One block per batch row b. Exact (t, slot) cumsum order.
// ---------------------------------------------------------------------------
__global__ __launch_bounds__(256) void scan_dispatch(
    const int* __restrict__ top2e, int* __restrict__ slot_row, int* __restrict__ row2tok)
{
    int b = blockIdx.x;
    int tid = threadIdx.x;
    __shared__ int cnt[256][8];
    int base = b * (TDIM * 2);
    int i0 = tid * 16;
    int c[8];
    #pragma unroll
    for (int e = 0; e < 8; e++) c[e] = 0;
    for (int j = 0; j < 16; j++){
        int e = top2e[base + i0 + j];
        c[e]++;
    }
    #pragma unroll
    for (int e = 0; e < 8; e++) cnt[tid][e] = c[e];
    __syncthreads();
    if (tid < 8){
        int run = 0;
        for (int t = 0; t < 256; t++){ int v = cnt[t][tid]; cnt[t][tid] = run; run += v; }
    }
    __syncthreads();
    int offs[8];
    #pragma unroll
    for (int e = 0; e < 8; e++) offs[e] = cnt[tid][e];
    for (int j = 0; j < 16; j++){
        int i = i0 + j;
        int e = top2e[base + i];
        int pos = offs[e]++;
        int r = (pos < CAPACITY) ? ((e * BDIM + b) * CAPACITY + pos) : -1;
        slot_row[base + i] = r;
        if (r >= 0) row2tok[r] = b * TDIM + (i >> 1);
    }
}

// ---------------------------------------------------------------------------
// K5: gather tokens into expert slot buffer (bf16). One block per slot row.
// ---------------------------------------------------------------------------
__global__ __launch_bounds__(256) void gather_rows(
    const float* __restrict__ x, const int* __restrict__ row2tok,
    unsigned short* __restrict__ Xe)
{
    int r = blockIdx.x;
    int tid = threadIdx.x;
    int tok = row2tok[r];
    unsigned short* dst = Xe + (size_t)r * CDIM + tid * 4;
    if (tok >= 0){
        float4 v = *(const float4*)(x + (size_t)tok * CDIM + tid * 4);
        ushort4 o;
        o.x = f2bf(v.x); o.y = f2bf(v.y); o.z = f2bf(v.z); o.w = f2bf(v.w);
        *(ushort4*)dst = o;
    } else {
        ushort4 o; o.x = o.y = o.z = o.w = 0;
        *(ushort4*)dst = o;
    }
}

// ---------------------------------------------------------------------------
// K8: combine. out[b,t,:] = s1*eout[r1,:] + s2*eout[r2,:] (dropped -> 0)
// ---------------------------------------------------------------------------
__global__ __launch_bounds__(256) void combine(
    const float* __restrict__ eout, const int* __restrict__ slot_row,
    const float* __restrict__ top2s, float* __restrict__ out)
{
    int gt = blockIdx.x;
    int b = gt >> 11, t = gt & (TDIM - 1);
    int i = b * (TDIM * 2) + t * 2;
    int r1 = slot_row[i], r2 = slot_row[i + 1];
    float s1 = top2s[gt*2 + 0], s2 = top2s[gt*2 + 1];
    int c = threadIdx.x * 4;
    float4 acc; acc.x = acc.y = acc.z = acc.w = 0.f;
    if (r1 >= 0){
        float4 v = *(const float4*)(eout + (size_t)r1 * CDIM + c);
        acc.x = fmaf(s1, v.x, acc.x); acc.y = fmaf(s1, v.y, acc.y);
        acc.z = fmaf(s1, v.z, acc.z); acc.w = fmaf(s1, v.w, acc.w);
    }
    if (r2 >= 0){
        float4 v = *(const float4*)(eout + (size_t)r2 * CDIM + c);
        acc.x = fmaf(s2, v.x, acc.x); acc.y = fmaf(s2, v.y, acc.y);
        acc.z = fmaf(s2, v.z, acc.z); acc.w = fmaf(s2, v.w, acc.w);
    }
    *(float4*)(out + (size_t)gt * CDIM + c) = acc;
}

// ---------------------------------------------------------------------------
extern "C" void kernel_launch(void* const* d_in, const int* in_sizes, int n_in,
                              void* d_out, int out_size, void* d_ws, size_t ws_size,
                              hipStream_t stream)
{
    const float* x   = (const float*)d_in[0];
    const float* rW1 = (const float*)d_in[1];
    const float* rb1 = (const float*)d_in[2];
    const float* rW2 = (const float*)d_in[3];
    const float* rb2 = (const float*)d_in[4];
    const float* rW3 = (const float*)d_in[5];
    const float* rb3 = (const float*)d_in[6];
    const float* eW1 = (const float*)d_in[7];
    const float* eb1 = (const float*)d_in[8];
    const float* eW2 = (const float*)d_in[9];
    const float* eb2 = (const float*)d_in[10];
    float* out = (float*)d_out;

    // workspace carve-up (all 256B aligned).
    // Persistent ~84.4 MB + UNION region:
    //   phase A (router, MCHUNK=4096, per-chunk x split): ~234.9 MB -> total ~319 MB
    //   phase B (experts, He for 2 experts): ~218 MB -> total ~302 MB
    // (both proven passing in r5)
    char* p = (char*)d_ws;
    auto alloc = [&](size_t bytes) -> void* {
        void* q = (void*)p;
        p += (bytes + 255) & ~(size_t)255;
        return q;
    };
    int*            top2e = (int*)alloc((size_t)MTOK * 2 * 4);
    float*          top2s = (float*)alloc((size_t)MTOK * 2 * 4);
    int*            slotr = (int*)alloc((size_t)BDIM * TDIM * 2 * 4);
    int*            r2tok = (int*)alloc((size_t)NROWS * 4);
    float*          eout  = (float*)alloc((size_t)NROWS * CDIM * 4);           // 84 MB
    char* ubase = p;

    // ---- phase A layout (router) ----
    unsigned short* Xchi  = (unsigned short*)alloc((size_t)MCHUNK * CDIM * 2); // 8.4 MB
    unsigned short* Xclo  = (unsigned short*)alloc((size_t)MCHUNK * CDIM * 2); // 8.4 MB
    unsigned short* W1thi = (unsigned short*)alloc((size_t)HDIM * CDIM * 2);   // 8.4 MB
    unsigned short* W1tlo = (unsigned short*)alloc((size_t)HDIM * CDIM * 2);   // 8.4 MB
    unsigned short* W2thi = (unsigned short*)alloc((size_t)HDIM * HDIM * 2);   // 33.5 MB
    unsigned short* W2tlo = (unsigned short*)alloc((size_t)HDIM * HDIM * 2);   // 33.5 MB
    unsigned short* H1hi  = (unsigned short*)alloc((size_t)MCHUNK * HDIM * 2); // 33.5 MB
    unsigned short* H1lo  = (unsigned short*)alloc((size_t)MCHUNK * HDIM * 2); // 33.5 MB
    float*          h2c   = (float*)alloc((size_t)MCHUNK * HDIM * 4);          // 67 MB

    // ---- phase B layout (experts) — aliases phase A ----
    p = ubase;
    unsigned short* Xe    = (unsigned short*)alloc((size_t)NROWS * CDIM * 2);      // 42 MB
    unsigned short* He    = (unsigned short*)alloc((size_t)2 * EROWS * HDIM * 2);  // 42 MB (2 experts)
    unsigned short* eW1t  = (unsigned short*)alloc((size_t)EDIM * HDIM * CDIM * 2); // 67 MB
    unsigned short* eW2t  = (unsigned short*)alloc((size_t)EDIM * CDIM * HDIM * 2); // 67 MB

    // 1) router weights -> fp16 hi/lo splits (transposed to [N][K])
    transpose_split<<<dim3(HDIM/32, CDIM/32), 256, 0, stream>>>(rW1, W1thi, W1tlo, CDIM, HDIM);
    transpose_split<<<dim3(HDIM/32, HDIM/32), 256, 0, stream>>>(rW2, W2thi, W2tlo, HDIM, HDIM);

    // 2) router, chunked over tokens (fp16x3 MFMA = fp32-accurate), 128^2 tiles
    for (int mc = 0; mc < NCHUNKS; mc++){
        split_f16<<<(MCHUNK * CDIM / 4 + 255) / 256, 256, 0, stream>>>(
            x + (size_t)mc * MCHUNK * CDIM, Xchi, Xclo, (size_t)MCHUNK * CDIM / 4);
        gemm_f16x3_128<<<dim3(MCHUNK/128, HDIM/128), 256, 0, stream>>>(
            Xchi, Xclo, W1thi, W1tlo, rb1, (void*)H1hi, (void*)H1lo, MCHUNK, HDIM, CDIM, 0);
        gemm_f16x3_128<<<dim3(MCHUNK/128, HDIM/128), 256, 0, stream>>>(
            H1hi, H1lo, W2thi, W2tlo, rb2, (void*)h2c, nullptr, MCHUNK, HDIM, HDIM, 1);
        router_head<<<MCHUNK/32, 256, 0, stream>>>(h2c, rW3, rb3, mc * MCHUNK, top2e, top2s);
    }

    // 3) dispatch (phase A buffers dead from here on)
    hipMemsetAsync(r2tok, 0xFF, (size_t)NROWS * 4, stream);
    scan_dispatch<<<BDIM, 256, 0, stream>>>(top2e, slotr, r2tok);
    gather_rows<<<NROWS, 256, 0, stream>>>(x, r2tok, Xe);

    // 4) expert weights -> bf16, transposed to [N][K]
    transpose_convert<<<dim3(HDIM/32, CDIM/32, EDIM), 256, 0, stream>>>(eW1, eW1t, CDIM, HDIM);
    transpose_convert<<<dim3(CDIM/32, HDIM/32, EDIM), 256, 0, stream>>>(eW2, eW2t, HDIM, CDIM);

    // 5) expert FFNs (bf16 MFMA), 2 experts per launch via grid.z
    for (int g = 0; g < EDIM/2; g++){
        int e0 = g * 2;
        gemm_bf16_128<<<dim3(EROWS/128, HDIM/128, 2), 256, 0, stream>>>(
            Xe + (size_t)e0 * EROWS * CDIM, eW1t + (size_t)e0 * HDIM * CDIM,
            eb1 + (size_t)e0 * HDIM, (void*)He,
            EROWS, HDIM, CDIM, 0,
            (size_t)EROWS * CDIM, (size_t)HDIM * CDIM, (size_t)HDIM, (size_t)EROWS * HDIM);
        gemm_bf16_128<<<dim3(EROWS/128, CDIM/128, 2), 256, 0, stream>>>(
            He, eW2t + (size_t)e0 * CDIM * HDIM,
            eb2 + (size_t)e0 * CDIM, (void*)(eout + (size_t)e0 * EROWS * CDIM),
            EROWS, CDIM, HDIM, 1,
            (size_t)EROWS * HDIM, (size_t)CDIM * HDIM, (size_t)CDIM, (size_t)EROWS * CDIM);
    }

    // 6) combine
    combine<<<MTOK, 256, 0, stream>>>(eout, slotr, top2s, out);
}

// Round 7
// 3295.922 us; speedup vs baseline: 3.0325x; 1.0714x over previous
//
#include <hip/hip_runtime.h>
#include <hip/hip_bf16.h>

// Problem constants
#define BDIM 8
#define TDIM 2048
#define CDIM 1024
#define HDIM 4096
#define EDIM 8
#define CAPACITY 320
#define MTOK (BDIM*TDIM)          // 16384
#define MCHUNK 4096               // router M-chunk (per-chunk x split keeps ws ~319 MB)
#define NCHUNKS (MTOK/MCHUNK)     // 4
#define EROWS (BDIM*CAPACITY)     // 2560 rows per expert
#define NROWS (EDIM*EROWS)        // 20480 total slots

typedef __attribute__((ext_vector_type(8))) short bf16x8;
typedef __attribute__((ext_vector_type(8))) _Float16 f16x8;
typedef __attribute__((ext_vector_type(4))) float f32x4;

__device__ __forceinline__ unsigned short f2bf(float f){
    __hip_bfloat16 h = __float2bfloat16(f);
    return *reinterpret_cast<unsigned short*>(&h);
}

// exact 2-term fp16 split: v = hi + lo + O(2^-22 * |v|)
__device__ __forceinline__ void f32_split(float v, unsigned short& h, unsigned short& l){
    _Float16 hh = (_Float16)v;         // RN
    float r = v - (float)hh;           // exact in fp32
    _Float16 ll = (_Float16)r;
    h = __builtin_bit_cast(unsigned short, hh);
    l = __builtin_bit_cast(unsigned short, ll);
}

// async global->LDS, 16B per lane. LDS dest is wave-uniform base + lane*16.
__device__ __forceinline__ void glds16(const unsigned short* g, unsigned short* l){
    __builtin_amdgcn_global_load_lds(
        (const __attribute__((address_space(1))) void*)g,
        (__attribute__((address_space(3))) void*)l,
        16, 0, 0);
}

// XCD-aware block swizzle, 2D per-XCD chunking.
// HW round-robins consecutive linear block ids across the 8 XCDs, so
// orig&7 == XCD id (grids here have nwg%8==0; z-slices preserve phase).
// Each XCD gets a SQUARE-ISH sub-grid (nbx/2 x nby/4) instead of a
// full-width stripe: per-XCD unique A-panel halves and A-slices are
// shared by only 2 XCDs (L3 catches the 2nd) -> shorter prefetch drains.
// Falls back to 1D chunking, then identity, when shapes don't divide.
__device__ __forceinline__ void xcd_tile(int& bx, int& by){
    int nbx = gridDim.x, nby = gridDim.y;
    int nwg = nbx * nby;
    int orig = blockIdx.y * nbx + blockIdx.x;
    if (((nwg & 7) == 0) && ((nbx & 1) == 0) && ((nby & 3) == 0)){
        int xcd = orig & 7;
        int loc = orig >> 3;          // [0, nwg/8)
        int hx = nbx >> 1, hy = nby >> 2;
        int bxl = loc % hx, byl = loc / hx;   // bx-fastest inside the XCD
        bx = (xcd & 1) * hx + bxl;
        by = (xcd >> 1) * hy + byl;
        return;
    }
    int wg = orig;
    if ((nwg & 7) == 0){
        int cpx = nwg >> 3;
        wg = (orig & 7) * cpx + (orig >> 3);
    }
    bx = wg % nbx;
    by = wg / nbx;
}

// ---------------------------------------------------------------------------
// K0: transpose + fp32->bf16 convert.  in: [z][R][Ccol] f32, out: [z][Ccol][R] bf16
// ---------------------------------------------------------------------------
__global__ __launch_bounds__(256) void transpose_convert(
    const float* __restrict__ in, unsigned short* __restrict__ out, int R, int Ccol)
{
    int z = blockIdx.z;
    in  += (size_t)z * R * Ccol;
    out += (size_t)z * R * Ccol;
    __shared__ float tile[32][33];
    int r0 = blockIdx.y * 32, c0 = blockIdx.x * 32;
    int tid = threadIdx.x;
    int lr = tid >> 5, lc = tid & 31;
    #pragma unroll
    for (int it = 0; it < 4; it++)
        tile[it*8 + lr][lc] = in[(size_t)(r0 + it*8 + lr) * Ccol + c0 + lc];
    __syncthreads();
    #pragma unroll
    for (int it = 0; it < 4; it++){
        float v = tile[lc][it*8 + lr];
        out[(size_t)(c0 + it*8 + lr) * R + r0 + lc] = f2bf(v);
    }
}

// ---------------------------------------------------------------------------
// K0b: transpose + fp32 -> fp16 hi/lo split.  in: [R][Ccol] f32, out hi/lo: [Ccol][R]
// ---------------------------------------------------------------------------
__global__ __launch_bounds__(256) void transpose_split(
    const float* __restrict__ in, unsigned short* __restrict__ hi,
    unsigned short* __restrict__ lo, int R, int Ccol)
{
    __shared__ float tile[32][33];
    int r0 = blockIdx.y * 32, c0 = blockIdx.x * 32;
    int tid = threadIdx.x;
    int lr = tid >> 5, lc = tid & 31;
    #pragma unroll
    for (int it = 0; it < 4; it++)
        tile[it*8 + lr][lc] = in[(size_t)(r0 + it*8 + lr) * Ccol + c0 + lc];
    __syncthreads();
    #pragma unroll
    for (int it = 0; it < 4; it++){
        float v = tile[lc][it*8 + lr];
        unsigned short h, l;
        f32_split(v, h, l);
        size_t o = (size_t)(c0 + it*8 + lr) * R + r0 + lc;
        hi[o] = h; lo[o] = l;
    }
}

// ---------------------------------------------------------------------------
// K0c: elementwise fp32 -> fp16 hi/lo split
// ---------------------------------------------------------------------------
__global__ __launch_bounds__(256) void split_f16(
    const float* __restrict__ in, unsigned short* __restrict__ hi,
    unsigned short* __restrict__ lo, size_t n4)
{
    size_t i = (size_t)blockIdx.x * 256 + threadIdx.x;
    if (i >= n4) return;
    float4 v = ((const float4*)in)[i];
    ushort4 h, l;
    f32_split(v.x, h.x, l.x);
    f32_split(v.y, h.y, l.y);
    f32_split(v.z, h.z, l.z);
    f32_split(v.w, h.w, l.w);
    ((ushort4*)hi)[i] = h;
    ((ushort4*)lo)[i] = l;
}

// ---------------------------------------------------------------------------
// K1/K2: fp32-accurate router GEMM, fp16x3 MFMA, 128x128 tile, BK=32,
// r4-PROVEN 2-phase dbuf: prefetch next K-tile -> ds_read cur -> MFMA ->
// single barrier (implicit vmcnt(0)+lgkmcnt(0) drain = correctness sync).
// 64 KiB LDS -> 2 blocks/CU; inter-block overlap hides the barrier drain.
// XOR-swizzle (both-sides): swz(byte) = byte ^ ((row&6)<<3) in 64B rows.
// mode 0: relu -> f16 hi/lo split outputs.  mode 1: relu -> f32 output.
// grid (M/128, N/128)
// ---------------------------------------------------------------------------
__global__ __launch_bounds__(256) void gemm_f16x3_128(
    const unsigned short* __restrict__ Ahi, const unsigned short* __restrict__ Alo,
    const unsigned short* __restrict__ Bthi, const unsigned short* __restrict__ Btlo,
    const float* __restrict__ bias, void* __restrict__ outA, void* __restrict__ outB,
    int M, int N, int K, int mode)
{
    __shared__ unsigned short AsH[2][128*32];  // [buf][row][k] linear, 64B rows
    __shared__ unsigned short AsL[2][128*32];
    __shared__ unsigned short BsH[2][128*32];
    __shared__ unsigned short BsL[2][128*32];
    int tid = threadIdx.x;
    int bx, by; xcd_tile(bx, by);
    int m0 = bx * 128, n0 = by * 128;
    int lane = tid & 63, w = tid >> 6;
    int wm = w & 1, wn = w >> 1;
    int l15 = lane & 15, quad = lane >> 4;

    f32x4 acc[4][4];
    #pragma unroll
    for (int i = 0; i < 4; i++)
        #pragma unroll
        for (int j = 0; j < 4; j++){ acc[i][j].x=0.f; acc[i][j].y=0.f; acc[i][j].z=0.f; acc[i][j].w=0.f; }

    // staging: wave w covers rows [w*32, w*32+32), 2 chunks x 16 rows.
    const unsigned short *pAh[2], *pAl[2], *pBh[2], *pBl[2];
    int wo[2];
    #pragma unroll
    for (int i = 0; i < 2; i++){
        int r0  = w*32 + i*16;
        int row = r0 + (lane >> 2);
        int ks  = ((lane & 3) * 8) ^ ((row & 6) << 2);   // shorts
        pAh[i] = Ahi  + (size_t)(m0 + row) * K + ks;
        pAl[i] = Alo  + (size_t)(m0 + row) * K + ks;
        pBh[i] = Bthi + (size_t)(n0 + row) * K + ks;
        pBl[i] = Btlo + (size_t)(n0 + row) * K + ks;
        wo[i]  = r0 * 32;
    }

    // fragment read byte-offsets (swizzled)
    int roA[4], roB[4];
    #pragma unroll
    for (int t = 0; t < 4; t++){
        int ra = wm*64 + t*16 + l15;
        roA[t] = (ra*64 + quad*16) ^ ((ra & 6) << 3);
        int rb = wn*64 + t*16 + l15;
        roB[t] = (rb*64 + quad*16) ^ ((rb & 6) << 3);
    }

    // prologue: stage K-tile 0 into buffer 0
    #pragma unroll
    for (int i = 0; i < 2; i++){
        glds16(pAh[i], &AsH[0][wo[i]]);
        glds16(pAl[i], &AsL[0][wo[i]]);
        glds16(pBh[i], &BsH[0][wo[i]]);
        glds16(pBl[i], &BsL[0][wo[i]]);
    }
    __syncthreads();

    int ntk = K >> 5;
    int cur = 0;
    for (int t = 0; t < ntk; t++){
        if (t + 1 < ntk){
            int ko = (t + 1) * 32;
            #pragma unroll
            for (int i = 0; i < 2; i++){
                glds16(pAh[i] + ko, &AsH[cur^1][wo[i]]);
                glds16(pAl[i] + ko, &AsL[cur^1][wo[i]]);
                glds16(pBh[i] + ko, &BsH[cur^1][wo[i]]);
                glds16(pBl[i] + ko, &BsL[cur^1][wo[i]]);
            }
        }
        f16x8 ah[4], al[4], bh[4], bl[4];
        #pragma unroll
        for (int t4 = 0; t4 < 4; t4++){
            ah[t4] = *(const f16x8*)((const char*)AsH[cur] + roA[t4]);
            al[t4] = *(const f16x8*)((const char*)AsL[cur] + roA[t4]);
            bh[t4] = *(const f16x8*)((const char*)BsH[cur] + roB[t4]);
            bl[t4] = *(const f16x8*)((const char*)BsL[cur] + roB[t4]);
        }
        __builtin_amdgcn_s_setprio(1);
        #pragma unroll
        for (int mt = 0; mt < 4; mt++)
            #pragma unroll
            for (int nt2 = 0; nt2 < 4; nt2++){
                acc[mt][nt2] = __builtin_amdgcn_mfma_f32_16x16x32_f16(ah[mt], bh[nt2], acc[mt][nt2], 0, 0, 0);
                acc[mt][nt2] = __builtin_amdgcn_mfma_f32_16x16x32_f16(ah[mt], bl[nt2], acc[mt][nt2], 0, 0, 0);
                acc[mt][nt2] = __builtin_amdgcn_mfma_f32_16x16x32_f16(al[mt], bh[nt2], acc[mt][nt2], 0, 0, 0);
            }
        __builtin_amdgcn_s_setprio(0);
        __syncthreads();
        cur ^= 1;
    }

    #pragma unroll
    for (int mt = 0; mt < 4; mt++)
        #pragma unroll
        for (int nt2 = 0; nt2 < 4; nt2++){
            int mb = m0 + wm*64 + mt*16 + quad*4;
            int n  = n0 + wn*64 + nt2*16 + l15;
            float bz = bias[n];
            #pragma unroll
            for (int r = 0; r < 4; r++){
                float v = fmaxf(acc[mt][nt2][r] + bz, 0.f);
                int m = mb + r;
                if (mode == 0){
                    unsigned short h, l;
                    f32_split(v, h, l);
                    ((unsigned short*)outA)[(size_t)m * N + n] = h;
                    ((unsigned short*)outB)[(size_t)m * N + n] = l;
                } else {
                    ((float*)outA)[(size_t)m * N + n] = v;
                }
            }
        }
}

// ---------------------------------------------------------------------------
// K6/K7: bf16 MFMA GEMM, 128x128 tile, BK=32, r4-proven dbuf/swizzle structure,
// expert-batched via blockIdx.z with per-z strides (elements).
// mode 0: relu -> bf16 out.  mode 1: plain -> f32 out.
// grid (M/128, N/128, nz)
// ---------------------------------------------------------------------------
__global__ __launch_bounds__(256) void gemm_bf16_128(
    const unsigned short* __restrict__ A, const unsigned short* __restrict__ Bt,
    const float* __restrict__ bias, void* __restrict__ outv,
    int M, int N, int K, int mode,
    size_t zsA, size_t zsB, size_t zsb, size_t zsO)
{
    __shared__ unsigned short As[2][128*32];
    __shared__ unsigned short Bs[2][128*32];
    int z = blockIdx.z;
    A    += (size_t)z * zsA;
    Bt   += (size_t)z * zsB;
    bias += (size_t)z * zsb;
    int tid = threadIdx.x;
    int bx, by; xcd_tile(bx, by);
    int m0 = bx * 128, n0 = by * 128;
    int lane = tid & 63, w = tid >> 6;
    int wm = w & 1, wn = w >> 1;
    int l15 = lane & 15, quad = lane >> 4;

    f32x4 acc[4][4];
    #pragma unroll
    for (int i = 0; i < 4; i++)
        #pragma unroll
        for (int j = 0; j < 4; j++){ acc[i][j].x=0.f; acc[i][j].y=0.f; acc[i][j].z=0.f; acc[i][j].w=0.f; }

    const unsigned short *pA[2], *pB[2];
    int wo[2];
    #pragma unroll
    for (int i = 0; i < 2; i++){
        int r0  = w*32 + i*16;
        int row = r0 + (lane >> 2);
        int ks  = ((lane & 3) * 8) ^ ((row & 6) << 2);
        pA[i] = A  + (size_t)(m0 + row) * K + ks;
        pB[i] = Bt + (size_t)(n0 + row) * K + ks;
        wo[i] = r0 * 32;
    }

    int roA[4], roB[4];
    #pragma unroll
    for (int t = 0; t < 4; t++){
        int ra = wm*64 + t*16 + l15;
        roA[t] = (ra*64 + quad*16) ^ ((ra & 6) << 3);
        int rb = wn*64 + t*16 + l15;
        roB[t] = (rb*64 + quad*16) ^ ((rb & 6) << 3);
    }

    #pragma unroll
    for (int i = 0; i < 2; i++){
        glds16(pA[i], &As[0][wo[i]]);
        glds16(pB[i], &Bs[0][wo[i]]);
    }
    __syncthreads();

    int ntk = K >> 5;
    int cur = 0;
    for (int t = 0; t < ntk; t++){
        if (t + 1 < ntk){
            int ko = (t + 1) * 32;
            #pragma unroll
            for (int i = 0; i < 2; i++){
                glds16(pA[i] + ko, &As[cur^1][wo[i]]);
                glds16(pB[i] + ko, &Bs[cur^1][wo[i]]);
            }
        }
        bf16x8 af[4], bf[4];
        #pragma unroll
        for (int t4 = 0; t4 < 4; t4++){
            af[t4] = *(const bf16x8*)((const char*)As[cur] + roA[t4]);
            bf[t4] = *(const bf16x8*)((const char*)Bs[cur] + roB[t4]);
        }
        __builtin_amdgcn_s_setprio(1);
        #pragma unroll
        for (int mt = 0; mt < 4; mt++)
            #pragma unroll
            for (int nt2 = 0; nt2 < 4; nt2++)
                acc[mt][nt2] = __builtin_amdgcn_mfma_f32_16x16x32_bf16(af[mt], bf[nt2], acc[mt][nt2], 0, 0, 0);
        __builtin_amdgcn_s_setprio(0);
        __syncthreads();
        cur ^= 1;
    }

    #pragma unroll
    for (int mt = 0; mt < 4; mt++)
        #pragma unroll
        for (int nt2 = 0; nt2 < 4; nt2++){
            int mb = m0 + wm*64 + mt*16 + quad*4;
            int n  = n0 + wn*64 + nt2*16 + l15;
            float bz = bias[n];
            #pragma unroll
            for (int r = 0; r < 4; r++){
                float v = acc[mt][nt2][r] + bz;
                int m = mb + r;
                if (mode == 0){
                    v = fmaxf(v, 0.f);
                    ((unsigned short*)outv)[(size_t)z * zsO + (size_t)m * N + n] = f2bf(v);
                } else {
                    ((float*)outv)[(size_t)z * zsO + (size_t)m * N + n] = v;
                }
            }
        }
}

// ---------------------------------------------------------------------------
// K3: router head. logits = h2 @ rW3 + rb3; softmax (double); top-2 w/ tie->low idx
// ---------------------------------------------------------------------------
__global__ __launch_bounds__(256) void router_head(
    const float* __restrict__ h2, const float* __restrict__ W3,
    const float* __restrict__ b3, int tokBase,
    int* __restrict__ top2e, float* __restrict__ top2s)
{
    int tid = threadIdx.x;
    int tloc = blockIdx.x * 32 + (tid >> 3);
    int e = tid & 7;
    const float* hrow = h2 + (size_t)tloc * HDIM;
    float acc = 0.f;
    for (int k = 0; k < HDIM; k += 4){
        float4 h = *(const float4*)(hrow + k);
        acc = fmaf(h.x, W3[(k+0)*8 + e], acc);
        acc = fmaf(h.y, W3[(k+1)*8 + e], acc);
        acc = fmaf(h.z, W3[(k+2)*8 + e], acc);
        acc = fmaf(h.w, W3[(k+3)*8 + e], acc);
    }
    float logit = acc + b3[e];
    __shared__ float lg[32][8];
    lg[tid >> 3][e] = logit;
    __syncthreads();
    if (tid < 32){
        double l[8];
        double mx = -1e300;
        for (int i = 0; i < 8; i++){ l[i] = (double)lg[tid][i]; if (l[i] > mx) mx = l[i]; }
        double ex[8]; double s = 0.0;
        for (int i = 0; i < 8; i++){ ex[i] = exp(l[i] - mx); s += ex[i]; }
        double b1v = -1.0, b2v = -1.0; int e1 = 0, e2 = 0;
        for (int i = 0; i < 8; i++){
            double v = ex[i];
            if (v > b1v){ b2v = b1v; e2 = e1; b1v = v; e1 = i; }
            else if (v > b2v){ b2v = v; e2 = i; }
        }
        int gt = tokBase + blockIdx.x * 32 + tid;
        top2e[gt*2 + 0] = e1;
        top2e[gt*2 + 1] = e2;
        top2s[gt*2 + 0] = (float)(b1v / s);
        top2s[gt*2 + 1] = (float)(b2v / s);
    }
}

// ---------------------------------------------------------------------------
// K4: dispatch scan. One block per batch row b. Exact (t, slot) cumsum order.
// ---------------------------------------------------------------------------
__global__ __launch_bounds__(256) void scan_dispatch(
    const int* __restrict__ top2e, int* __restrict__ slot_row, int* __restrict__ row2tok)
{
    int b = blockIdx.x;
    int tid = threadIdx.x;
    __shared__ int cnt[256][8];
    int base = b * (TDIM * 2);
    int i0 = tid * 16;
    int c[8];
    #pragma unroll
    for (int e = 0; e < 8; e++) c[e] = 0;
    for (int j = 0; j < 16; j++){
        int e = top2e[base + i0 + j];
        c[e]++;
    }
    #pragma unroll
    for (int e = 0; e < 8; e++) cnt[tid][e] = c[e];
    __syncthreads();
    if (tid < 8){
        int run = 0;
        for (int t = 0; t < 256; t++){ int v = cnt[t][tid]; cnt[t][tid] = run; run += v; }
    }
    __syncthreads();
    int offs[8];
    #pragma unroll
    for (int e = 0; e < 8; e++) offs[e] = cnt[tid][e];
    for (int j = 0; j < 16; j++){
        int i = i0 + j;
        int e = top2e[base + i];
        int pos = offs[e]++;
        int r = (pos < CAPACITY) ? ((e * BDIM + b) * CAPACITY + pos) : -1;
        slot_row[base + i] = r;
        if (r >= 0) row2tok[r] = b * TDIM + (i >> 1);
    }
}

// ---------------------------------------------------------------------------
// K5: gather tokens into expert slot buffer (bf16). One block per slot row.
// ---------------------------------------------------------------------------
__global__ __launch_bounds__(256) void gather_rows(
    const float* __restrict__ x, const int* __restrict__ row2tok,
    unsigned short* __restrict__ Xe)
{
    int r = blockIdx.x;
    int tid = threadIdx.x;
    int tok = row2tok[r];
    unsigned short* dst = Xe + (size_t)r * CDIM + tid * 4;
    if (tok >= 0){
        float4 v = *(const float4*)(x + (size_t)tok * CDIM + tid * 4);
        ushort4 o;
        o.x = f2bf(v.x); o.y = f2bf(v.y); o.z = f2bf(v.z); o.w = f2bf(v.w);
        *(ushort4*)dst = o;
    } else {
        ushort4 o; o.x = o.y = o.z = o.w = 0;
        *(ushort4*)dst = o;
    }
}

// ---------------------------------------------------------------------------
// K8: combine. out[b,t,:] = s1*eout[r1,:] + s2*eout[r2,:] (dropped -> 0)
// ---------------------------------------------------------------------------
__global__ __launch_bounds__(256) void combine(
    const float* __restrict__ eout, const int* __restrict__ slot_row,
    const float* __restrict__ top2s, float* __restrict__ out)
{
    int gt = blockIdx.x;
    int b = gt >> 11, t = gt & (TDIM - 1);
    int i = b * (TDIM * 2) + t * 2;
    int r1 = slot_row[i], r2 = slot_row[i + 1];
    float s1 = top2s[gt*2 + 0], s2 = top2s[gt*2 + 1];
    int c = threadIdx.x * 4;
    float4 acc; acc.x = acc.y = acc.z = acc.w = 0.f;
    if (r1 >= 0){
        float4 v = *(const float4*)(eout + (size_t)r1 * CDIM + c);
        acc.x = fmaf(s1, v.x, acc.x); acc.y = fmaf(s1, v.y, acc.y);
        acc.z = fmaf(s1, v.z, acc.z); acc.w = fmaf(s1, v.w, acc.w);
    }
    if (r2 >= 0){
        float4 v = *(const float4*)(eout + (size_t)r2 * CDIM + c);
        acc.x = fmaf(s2, v.x, acc.x); acc.y = fmaf(s2, v.y, acc.y);
        acc.z = fmaf(s2, v.z, acc.z); acc.w = fmaf(s2, v.w, acc.w);
    }
    *(float4*)(out + (size_t)gt * CDIM + c) = acc;
}

// ---------------------------------------------------------------------------
extern "C" void kernel_launch(void* const* d_in, const int* in_sizes, int n_in,
                              void* d_out, int out_size, void* d_ws, size_t ws_size,
                              hipStream_t stream)
{
    const float* x   = (const float*)d_in[0];
    const float* rW1 = (const float*)d_in[1];
    const float* rb1 = (const float*)d_in[2];
    const float* rW2 = (const float*)d_in[3];
    const float* rb2 = (const float*)d_in[4];
    const float* rW3 = (const float*)d_in[5];
    const float* rb3 = (const float*)d_in[6];
    const float* eW1 = (const float*)d_in[7];
    const float* eb1 = (const float*)d_in[8];
    const float* eW2 = (const float*)d_in[9];
    const float* eb2 = (const float*)d_in[10];
    float* out = (float*)d_out;

    // workspace carve-up (all 256B aligned).
    // Persistent ~84.4 MB + UNION region:
    //   phase A (router, MCHUNK=4096, per-chunk x split): ~234.9 MB -> total ~319 MB
    //   phase B (experts, He for 2 experts): ~218 MB -> total ~302 MB
    // (both proven passing in r5/r6)
    char* p = (char*)d_ws;
    auto alloc = [&](size_t bytes) -> void* {
        void* q = (void*)p;
        p += (bytes + 255) & ~(size_t)255;
        return q;
    };
    int*            top2e = (int*)alloc((size_t)MTOK * 2 * 4);
    float*          top2s = (float*)alloc((size_t)MTOK * 2 * 4);
    int*            slotr = (int*)alloc((size_t)BDIM * TDIM * 2 * 4);
    int*            r2tok = (int*)alloc((size_t)NROWS * 4);
    float*          eout  = (float*)alloc((size_t)NROWS * CDIM * 4);           // 84 MB
    char* ubase = p;

    // ---- phase A layout (router) ----
    unsigned short* Xchi  = (unsigned short*)alloc((size_t)MCHUNK * CDIM * 2); // 8.4 MB
    unsigned short* Xclo  = (unsigned short*)alloc((size_t)MCHUNK * CDIM * 2); // 8.4 MB
    unsigned short* W1thi = (unsigned short*)alloc((size_t)HDIM * CDIM * 2);   // 8.4 MB
    unsigned short* W1tlo = (unsigned short*)alloc((size_t)HDIM * CDIM * 2);   // 8.4 MB
    unsigned short* W2thi = (unsigned short*)alloc((size_t)HDIM * HDIM * 2);   // 33.5 MB
    unsigned short* W2tlo = (unsigned short*)alloc((size_t)HDIM * HDIM * 2);   // 33.5 MB
    unsigned short* H1hi  = (unsigned short*)alloc((size_t)MCHUNK * HDIM * 2); // 33.5 MB
    unsigned short* H1lo  = (unsigned short*)alloc((size_t)MCHUNK * HDIM * 2); // 33.5 MB
    float*          h2c   = (float*)alloc((size_t)MCHUNK * HDIM * 4);          // 67 MB

    // ---- phase B layout (experts) — aliases phase A ----
    p = ubase;
    unsigned short* Xe    = (unsigned short*)alloc((size_t)NROWS * CDIM * 2);      // 42 MB
    unsigned short* He    = (unsigned short*)alloc((size_t)2 * EROWS * HDIM * 2);  // 42 MB (2 experts)
    unsigned short* eW1t  = (unsigned short*)alloc((size_t)EDIM * HDIM * CDIM * 2); // 67 MB
    unsigned short* eW2t  = (unsigned short*)alloc((size_t)EDIM * CDIM * HDIM * 2); // 67 MB

    // 1) router weights -> fp16 hi/lo splits (transposed to [N][K])
    transpose_split<<<dim3(HDIM/32, CDIM/32), 256, 0, stream>>>(rW1, W1thi, W1tlo, CDIM, HDIM);
    transpose_split<<<dim3(HDIM/32, HDIM/32), 256, 0, stream>>>(rW2, W2thi, W2tlo, HDIM, HDIM);

    // 2) router, chunked over tokens (fp16x3 MFMA = fp32-accurate), 128^2 tiles
    for (int mc = 0; mc < NCHUNKS; mc++){
        split_f16<<<(MCHUNK * CDIM / 4 + 255) / 256, 256, 0, stream>>>(
            x + (size_t)mc * MCHUNK * CDIM, Xchi, Xclo, (size_t)MCHUNK * CDIM / 4);
        gemm_f16x3_128<<<dim3(MCHUNK/128, HDIM/128), 256, 0, stream>>>(
            Xchi, Xclo, W1thi, W1tlo, rb1, (void*)H1hi, (void*)H1lo, MCHUNK, HDIM, CDIM, 0);
        gemm_f16x3_128<<<dim3(MCHUNK/128, HDIM/128), 256, 0, stream>>>(
            H1hi, H1lo, W2thi, W2tlo, rb2, (void*)h2c, nullptr, MCHUNK, HDIM, HDIM, 1);
        router_head<<<MCHUNK/32, 256, 0, stream>>>(h2c, rW3, rb3, mc * MCHUNK, top2e, top2s);
    }

    // 3) dispatch (phase A buffers dead from here on)
    hipMemsetAsync(r2tok, 0xFF, (size_t)NROWS * 4, stream);
    scan_dispatch<<<BDIM, 256, 0, stream>>>(top2e, slotr, r2tok);
    gather_rows<<<NROWS, 256, 0, stream>>>(x, r2tok, Xe);

    // 4) expert weights -> bf16, transposed to [N][K]
    transpose_convert<<<dim3(HDIM/32, CDIM/32, EDIM), 256, 0, stream>>>(eW1, eW1t, CDIM, HDIM);
    transpose_convert<<<dim3(CDIM/32, HDIM/32, EDIM), 256, 0, stream>>>(eW2, eW2t, HDIM, CDIM);

    // 5) expert FFNs (bf16 MFMA), 2 experts per launch via grid.z
    for (int g = 0; g < EDIM/2; g++){
        int e0 = g * 2;
        gemm_bf16_128<<<dim3(EROWS/128, HDIM/128, 2), 256, 0, stream>>>(
            Xe + (size_t)e0 * EROWS * CDIM, eW1t + (size_t)e0 * HDIM * CDIM,
            eb1 + (size_t)e0 * HDIM, (void*)He,
            EROWS, HDIM, CDIM, 0,
            (size_t)EROWS * CDIM, (size_t)HDIM * CDIM, (size_t)HDIM, (size_t)EROWS * HDIM);
        gemm_bf16_128<<<dim3(EROWS/128, CDIM/128, 2), 256, 0, stream>>>(
            He, eW2t + (size_t)e0 * CDIM * HDIM,
            eb2 + (size_t)e0 * CDIM, (void*)(eout + (size_t)e0 * EROWS * CDIM),
            EROWS, CDIM, HDIM, 1,
            (size_t)EROWS * HDIM, (size_t)CDIM * HDIM, (size_t)CDIM, (size_t)EROWS * CDIM);
    }

    // 6) combine
    combine<<<MTOK, 256, 0, stream>>>(eout, slotr, top2s, out);
}